// Round 1
// baseline (963.809 us; speedup 1.0000x reference)
//
#include <hip/hip_runtime.h>
#include <math.h>

// 2-layer GAT: N nodes, E directed edges (+ self loops added per layer).
// Layer1: 128 -> 8 heads x 16 (concat=128), ELU. Layer2: 128 -> 1 head x 40, log_softmax.

__device__ __forceinline__ float lrelu02(float x){ return x > 0.f ? x : 0.2f*x; }

// ---------------- graph build: CSR by destination ----------------
__global__ void k_count(const int* __restrict__ dst, int* __restrict__ deg, int E){
  int i = blockIdx.x*blockDim.x + threadIdx.x;
  if (i < E) atomicAdd(&deg[dst[i]], 1);
}

// block scans 1024 elements (4/thread), writes local exclusive prefix + block total
__global__ void k_scanA(const int* __restrict__ deg, int* __restrict__ rowstart,
                        int* __restrict__ bsum, int N){
  __shared__ int lds[256];
  int t = threadIdx.x;
  int base = blockIdx.x*1024 + t*4;
  int v0 = (base+0<N)?deg[base+0]:0;
  int v1 = (base+1<N)?deg[base+1]:0;
  int v2 = (base+2<N)?deg[base+2]:0;
  int v3 = (base+3<N)?deg[base+3]:0;
  lds[t] = v0+v1+v2+v3;
  __syncthreads();
  for (int off=1; off<256; off<<=1){
    int x = (t>=off)? lds[t-off] : 0;
    __syncthreads();
    lds[t] += x;
    __syncthreads();
  }
  int run = (t==0)? 0 : lds[t-1];
  if (base+0<N) rowstart[base+0]=run;
  run += v0;
  if (base+1<N) rowstart[base+1]=run;
  run += v1;
  if (base+2<N) rowstart[base+2]=run;
  run += v2;
  if (base+3<N) rowstart[base+3]=run;
  if (t==255) bsum[blockIdx.x] = lds[255];
}

__global__ void k_scanB(int* bsum, int nblk){
  __shared__ int lds[128];
  int t = threadIdx.x;
  lds[t] = (t<nblk)? bsum[t] : 0;
  __syncthreads();
  for (int off=1; off<128; off<<=1){
    int x = (t>=off)? lds[t-off] : 0;
    __syncthreads();
    lds[t] += x;
    __syncthreads();
  }
  if (t<nblk) bsum[t] = (t==0)? 0 : lds[t-1];
}

__global__ void k_scanC(int* rowstart, const int* __restrict__ bsum, int N, int E){
  int i = blockIdx.x*blockDim.x + threadIdx.x;
  if (i < N) rowstart[i] += bsum[i>>10];
  if (i == 0) rowstart[N] = E;
}

__global__ void k_fill(const int* __restrict__ src, const int* __restrict__ dst,
                       const int* __restrict__ rowstart, int* __restrict__ fillc,
                       int* __restrict__ csr, int E){
  int i = blockIdx.x*blockDim.x + threadIdx.x;
  if (i < E){
    int d = dst[i];
    int pos = rowstart[d] + atomicAdd(&fillc[d], 1);
    csr[pos] = src[i];
  }
}

// ---------------- GEMM1: h1[N,128] = x @ W1^T + b1 ----------------
// W staged in LDS in k4-major permuted layout: element (oc,k) at float idx (k>>2)*512 + oc*4 + (k&3)
// -> wave b128 reads (lanes = consecutive oc) spread evenly across all 32 banks.
__global__ __launch_bounds__(256) void k_gemm1(const float* __restrict__ x,
    const float* __restrict__ W, const float* __restrict__ b,
    float* __restrict__ h, int N){
  __shared__ float Wl[16384]; // 64 KB
  for (int i = threadIdx.x; i < 16384; i += 256){
    int oc = i >> 7, k = i & 127;
    Wl[((k>>2)<<9) + (oc<<2) + (k&3)] = W[i];
  }
  __syncthreads();
  int oc = threadIdx.x & 127;
  int which = threadIdx.x >> 7;
  const float4* W4 = (const float4*)Wl;
  float bb = b[oc];
  for (int n0 = blockIdx.x*2; n0 < N; n0 += gridDim.x*2){
    int n = n0 + which;
    if (n < N){
      const float4* xr = (const float4*)(x + (size_t)n*128);
      float acc = 0.f;
      #pragma unroll 8
      for (int k4 = 0; k4 < 32; ++k4){
        float4 xv = xr[k4];            // same addr across 64 lanes -> broadcast, L1-hit
        float4 wv = W4[(k4<<7) + oc];  // conflict-free spread
        acc += xv.x*wv.x + xv.y*wv.y + xv.z*wv.z + xv.w*wv.w;
      }
      h[(size_t)n*128 + oc] = acc + bb;
    }
  }
}

// ---------------- attention scalars layer 1: a1i/a1j [N,8] ----------------
__global__ void k_att1(const float* __restrict__ h, const float* __restrict__ att,
                       float* __restrict__ ai, float* __restrict__ aj, int N){
  int i = blockIdx.x*blockDim.x + threadIdx.x; // n*8 + head
  if (i >= N*8) return;
  int hd = i & 7;
  const float* hp = h + (size_t)(i>>3)*128 + hd*16;
  const float* ap = att + hd*32;
  float si = 0.f, sj = 0.f;
  #pragma unroll
  for (int c = 0; c < 16; ++c){ float v = hp[c]; si += v*ap[c]; sj += v*ap[16+c]; }
  ai[i] = si; aj[i] = sj;
}

// ---------------- layer-1 segment softmax + aggregate + bias + ELU ----------------
// one wave per node. Phase1: lane = (edge-slot = lane>>3, head = lane&7), online max/denom,
// butterfly-combine over xor {8,16,32}. Phase2: lane owns channels (2l,2l+1), head = l>>3.
__global__ __launch_bounds__(256) void k_agg1(const float* __restrict__ h1,
    const float* __restrict__ a1i, const float* __restrict__ a1j,
    const int* __restrict__ rowstart, const int* __restrict__ csr,
    const float* __restrict__ bias, float* __restrict__ x2, int N){
  int lane = threadIdx.x & 63;
  int n = (blockIdx.x*blockDim.x + threadIdx.x) >> 6;
  if (n >= N) return;
  int rs = rowstart[n], re = rowstart[n+1];
  int hd = lane & 7, grp = lane >> 3;
  float aih = a1i[n*8 + hd];
  float es0 = lrelu02(aih + a1j[n*8 + hd]);   // self loop
  float m    = (grp==0)? es0 : -INFINITY;
  float dsum = (grp==0)? 1.f : 0.f;
  for (int ei = rs + grp; ei < re; ei += 8){
    int s = csr[ei];
    float e = lrelu02(aih + a1j[s*8 + hd]);
    if (e > m){ dsum = dsum*__expf(m - e) + 1.f; m = e; }
    else dsum += __expf(e - m);
  }
  #pragma unroll
  for (int off = 8; off < 64; off <<= 1){
    float mo  = __shfl_xor(m, off);
    float dso = __shfl_xor(dsum, off);
    float M = fmaxf(m, mo);
    float t1 = (dsum > 0.f)? dsum*__expf(m - M) : 0.f;
    float t2 = (dso  > 0.f)? dso *__expf(mo - M) : 0.f;
    m = M; dsum = t1 + t2;
  }
  // redistribute: lane l needs head l>>3; lane (l>>3) in 0..7 holds exactly that head
  int hd2 = lane >> 3;
  float mh = __shfl(m, hd2);
  float dh = __shfl(dsum, hd2);
  float invd = 1.f/(dh + 1e-16f);
  float ai2 = a1i[n*8 + hd2];
  const float2* hv2 = (const float2*)h1;
  float acc0, acc1;
  {
    float e = lrelu02(ai2 + a1j[n*8 + hd2]);
    float w = __expf(e - mh)*invd;
    float2 hv = hv2[(size_t)n*64 + lane];
    acc0 = w*hv.x; acc1 = w*hv.y;
  }
  for (int ei = rs; ei < re; ++ei){
    int s = csr[ei];
    float e = lrelu02(ai2 + a1j[s*8 + hd2]);
    float w = __expf(e - mh)*invd;
    float2 hv = hv2[(size_t)s*64 + lane];   // 512B coalesced gather
    acc0 += w*hv.x; acc1 += w*hv.y;
  }
  float o0 = acc0 + bias[2*lane];
  float o1 = acc1 + bias[2*lane+1];
  o0 = (o0 > 0.f)? o0 : (__expf(o0) - 1.f);  // ELU fused
  o1 = (o1 > 0.f)? o1 : (__expf(o1) - 1.f);
  ((float2*)x2)[(size_t)n*64 + lane] = make_float2(o0, o1);
}

// ---------------- GEMM2: h2[N,40] = x2 @ W2^T + b2 ----------------
__global__ __launch_bounds__(320) void k_gemm2(const float* __restrict__ x,
    const float* __restrict__ W, const float* __restrict__ b,
    float* __restrict__ h, int N){
  __shared__ float Wl[5120]; // 20 KB, k4-major: (oc,k) -> (k>>2)*160 + oc*4 + (k&3)
  for (int i = threadIdx.x; i < 5120; i += 320){
    int oc = i >> 7, k = i & 127;
    Wl[(k>>2)*160 + (oc<<2) + (k&3)] = W[i];
  }
  __syncthreads();
  int oc = threadIdx.x % 40;
  int which = threadIdx.x / 40;
  const float4* W4 = (const float4*)Wl;
  float bb = b[oc];
  for (int n0 = blockIdx.x*8; n0 < N; n0 += gridDim.x*8){
    int n = n0 + which;
    if (n < N){
      const float4* xr = (const float4*)(x + (size_t)n*128);
      float acc = 0.f;
      #pragma unroll 8
      for (int k4 = 0; k4 < 32; ++k4){
        float4 xv = xr[k4];
        float4 wv = W4[k4*40 + oc];
        acc += xv.x*wv.x + xv.y*wv.y + xv.z*wv.z + xv.w*wv.w;
      }
      h[(size_t)n*40 + oc] = acc + bb;
    }
  }
}

__global__ void k_att2(const float* __restrict__ h, const float* __restrict__ att,
                       float* __restrict__ ai, float* __restrict__ aj, int N){
  int n = blockIdx.x*blockDim.x + threadIdx.x;
  if (n >= N) return;
  const float* hp = h + (size_t)n*40;
  float si = 0.f, sj = 0.f;
  #pragma unroll
  for (int c = 0; c < 40; ++c){ float v = hp[c]; si += v*att[c]; sj += v*att[40+c]; }
  ai[n] = si; aj[n] = sj;
}

// ---------------- layer-2 aggregate (+bias) + log_softmax ----------------
__global__ __launch_bounds__(256) void k_agg2(const float* __restrict__ h2,
    const float* __restrict__ a2i, const float* __restrict__ a2j,
    const int* __restrict__ rowstart, const int* __restrict__ csr,
    const float* __restrict__ bias, float* __restrict__ out, int N){
  int lane = threadIdx.x & 63;
  int n = (blockIdx.x*blockDim.x + threadIdx.x) >> 6;
  if (n >= N) return;
  int rs = rowstart[n], re = rowstart[n+1];
  float ai = a2i[n];
  float es = lrelu02(ai + a2j[n]);            // self loop
  float m    = (lane==0)? es : -INFINITY;
  float dsum = (lane==0)? 1.f : 0.f;
  for (int ei = rs + lane; ei < re; ei += 64){
    int s = csr[ei];
    float e = lrelu02(ai + a2j[s]);
    if (e > m){ dsum = dsum*__expf(m - e) + 1.f; m = e; }
    else dsum += __expf(e - m);
  }
  #pragma unroll
  for (int off = 1; off < 64; off <<= 1){
    float mo  = __shfl_xor(m, off);
    float dso = __shfl_xor(dsum, off);
    float M = fmaxf(m, mo);
    float t1 = (dsum > 0.f)? dsum*__expf(m - M) : 0.f;
    float t2 = (dso  > 0.f)? dso *__expf(mo - M) : 0.f;
    m = M; dsum = t1 + t2;
  }
  float invd = 1.f/(dsum + 1e-16f);
  bool act = lane < 40;
  float acc = 0.f;
  {
    float w = __expf(es - m)*invd;
    if (act) acc = w*h2[(size_t)n*40 + lane];
  }
  for (int ei = rs; ei < re; ++ei){
    int s = csr[ei];
    float e = lrelu02(ai + a2j[s]);
    float w = __expf(e - m)*invd;
    if (act) acc += w*h2[(size_t)s*40 + lane];
  }
  float v = acc + (act? bias[lane] : 0.f);
  float mv = act? v : -INFINITY;
  #pragma unroll
  for (int off = 1; off < 64; off <<= 1) mv = fmaxf(mv, __shfl_xor(mv, off));
  float se = act? __expf(v - mv) : 0.f;
  #pragma unroll
  for (int off = 1; off < 64; off <<= 1) se += __shfl_xor(se, off);
  if (act) out[(size_t)n*40 + lane] = v - mv - __logf(se);
}

extern "C" void kernel_launch(void* const* d_in, const int* in_sizes, int n_in,
                              void* d_out, int out_size, void* d_ws, size_t ws_size,
                              hipStream_t stream){
  const float* x     = (const float*)d_in[0];
  const int*   ei    = (const int*)  d_in[1];
  const float* W1    = (const float*)d_in[2];
  const float* b1    = (const float*)d_in[3];
  const float* att1  = (const float*)d_in[4];
  const float* bias1 = (const float*)d_in[5];
  const float* W2    = (const float*)d_in[6];
  const float* b2    = (const float*)d_in[7];
  const float* att2  = (const float*)d_in[8];
  const float* bias2 = (const float*)d_in[9];
  int N = in_sizes[0] / 128;
  int E = in_sizes[1] / 2;
  const int* src = ei;
  const int* dst = ei + E;

  char* ws = (char*)d_ws;
  size_t off = 0;
  auto alloc = [&](size_t bytes)->char*{
    char* p = ws + off; off += (bytes + 255) & ~(size_t)255; return p;
  };
  float* h1   = (float*)alloc((size_t)N*128*4);
  float* x2   = (float*)alloc((size_t)N*128*4);
  float* h2   = (float*)alloc((size_t)N*40*4);
  float* a1i  = (float*)alloc((size_t)N*8*4);
  float* a1j  = (float*)alloc((size_t)N*8*4);
  float* a2i  = (float*)alloc((size_t)N*4);
  float* a2j  = (float*)alloc((size_t)N*4);
  int*   deg  = (int*)  alloc((size_t)N*4*2);  // deg + fill contiguous (one memset)
  int*   fillc= deg + N;
  int*   rowst= (int*)  alloc((size_t)(N+1)*4);
  int*   csr  = (int*)  alloc((size_t)E*4);
  int*   bsum = (int*)  alloc(4096);

  hipMemsetAsync(deg, 0, (size_t)N*8, stream);
  int nblk = (N + 1023)/1024;
  k_count<<<(E+255)/256, 256, 0, stream>>>(dst, deg, E);
  k_scanA<<<nblk, 256, 0, stream>>>(deg, rowst, bsum, N);
  k_scanB<<<1, 128, 0, stream>>>(bsum, nblk);
  k_scanC<<<(N+255)/256, 256, 0, stream>>>(rowst, bsum, N, E);
  k_fill<<<(E+255)/256, 256, 0, stream>>>(src, dst, rowst, fillc, csr, E);

  k_gemm1<<<1024, 256, 0, stream>>>(x, W1, b1, h1, N);
  k_att1<<<(N*8+255)/256, 256, 0, stream>>>(h1, att1, a1i, a1j, N);
  k_agg1<<<(N*64+255)/256, 256, 0, stream>>>(h1, a1i, a1j, rowst, csr, bias1, x2, N);

  k_gemm2<<<1250, 320, 0, stream>>>(x2, W2, b2, h2, N);
  k_att2<<<(N+255)/256, 256, 0, stream>>>(h2, att2, a2i, a2j, N);
  k_agg2<<<(N*64+255)/256, 256, 0, stream>>>(h2, a2i, a2j, rowst, csr, bias2, (float*)d_out, N);
}

// Round 2
// 963.530 us; speedup vs baseline: 1.0003x; 1.0003x over previous
//
#include <hip/hip_runtime.h>
#include <math.h>

// 2-layer GAT: N nodes, E directed edges (+ self loops added per layer).
// Layer1: 128 -> 8 heads x 16 (concat=128), ELU. Layer2: 128 -> 1 head x 40, log_softmax.

__device__ __forceinline__ float lrelu02(float x){ return x > 0.f ? x : 0.2f*x; }

// ---------------- graph build: CSR by destination ----------------
__global__ void k_count(const int* __restrict__ dst, int* __restrict__ deg, int E){
  int i = blockIdx.x*blockDim.x + threadIdx.x;
  if (i < E) atomicAdd(&deg[dst[i]], 1);
}

// block scans 1024 elements (4/thread), writes local exclusive prefix + block total
__global__ void k_scanA(const int* __restrict__ deg, int* __restrict__ rowstart,
                        int* __restrict__ bsum, int N){
  __shared__ int lds[256];
  int t = threadIdx.x;
  int base = blockIdx.x*1024 + t*4;
  int v0 = (base+0<N)?deg[base+0]:0;
  int v1 = (base+1<N)?deg[base+1]:0;
  int v2 = (base+2<N)?deg[base+2]:0;
  int v3 = (base+3<N)?deg[base+3]:0;
  lds[t] = v0+v1+v2+v3;
  __syncthreads();
  for (int off=1; off<256; off<<=1){
    int x = (t>=off)? lds[t-off] : 0;
    __syncthreads();
    lds[t] += x;
    __syncthreads();
  }
  int run = (t==0)? 0 : lds[t-1];
  if (base+0<N) rowstart[base+0]=run;
  run += v0;
  if (base+1<N) rowstart[base+1]=run;
  run += v1;
  if (base+2<N) rowstart[base+2]=run;
  run += v2;
  if (base+3<N) rowstart[base+3]=run;
  if (t==255) bsum[blockIdx.x] = lds[255];
}

__global__ void k_scanB(int* bsum, int nblk){
  __shared__ int lds[128];
  int t = threadIdx.x;
  lds[t] = (t<nblk)? bsum[t] : 0;
  __syncthreads();
  for (int off=1; off<128; off<<=1){
    int x = (t>=off)? lds[t-off] : 0;
    __syncthreads();
    lds[t] += x;
    __syncthreads();
  }
  if (t<nblk) bsum[t] = (t==0)? 0 : lds[t-1];
}

__global__ void k_scanC(int* rowstart, const int* __restrict__ bsum, int N, int E){
  int i = blockIdx.x*blockDim.x + threadIdx.x;
  if (i < N) rowstart[i] += bsum[i>>10];
  if (i == 0) rowstart[N] = E;
}

__global__ void k_fill(const int* __restrict__ src, const int* __restrict__ dst,
                       const int* __restrict__ rowstart, int* __restrict__ fillc,
                       int* __restrict__ csr, int E){
  int i = blockIdx.x*blockDim.x + threadIdx.x;
  if (i < E){
    int d = dst[i];
    int pos = rowstart[d] + atomicAdd(&fillc[d], 1);
    csr[pos] = src[i];
  }
}

// ---------------- GEMM1: h1[N,128] = x @ W1^T + b1 ----------------
// blockIdx.y selects an oc-half (64 oc). W half staged in LDS (32 KB) in k4-major
// layout: element (oc_local,k) at float idx (k>>2)*256 + oc_local*4 + (k&3).
// Thread = (oc_local = t&63, node-group = t>>6). Each thread: 4 nodes x 1 oc ->
// 4 independent FMA chains; one ds_read_b128 of W serves 16 FMAs. x loads are
// wave-uniform broadcasts (1 line/instr, L1-hit).
__global__ __launch_bounds__(256) void k_gemm1(const float* __restrict__ x,
    const float* __restrict__ W, const float* __restrict__ b,
    float* __restrict__ h, int N){
  __shared__ float Wl[8192]; // 32 KB: 64 oc x 128 k
  int och = blockIdx.y << 6;
  for (int i = threadIdx.x; i < 8192; i += 256){
    int oc = i >> 7, k = i & 127;
    Wl[((k>>2)<<8) + (oc<<2) + (k&3)] = W[(size_t)(och+oc)*128 + k];
  }
  __syncthreads();
  int ocl = threadIdx.x & 63;
  int ng  = threadIdx.x >> 6;       // 0..3
  int ocg = och + ocl;
  const float4* W4 = (const float4*)Wl;
  float bb = b[ocg];
  for (int n0 = blockIdx.x*16 + ng*4; n0 < N; n0 += gridDim.x*16){
    int m0 = min(n0+0, N-1), m1 = min(n0+1, N-1), m2 = min(n0+2, N-1), m3 = min(n0+3, N-1);
    const float4* xr0 = (const float4*)(x + (size_t)m0*128);
    const float4* xr1 = (const float4*)(x + (size_t)m1*128);
    const float4* xr2 = (const float4*)(x + (size_t)m2*128);
    const float4* xr3 = (const float4*)(x + (size_t)m3*128);
    float a0 = 0.f, a1 = 0.f, a2 = 0.f, a3 = 0.f;
    #pragma unroll 8
    for (int k4 = 0; k4 < 32; ++k4){
      float4 wv = W4[(k4<<6) + ocl];
      float4 x0 = xr0[k4], x1 = xr1[k4], x2 = xr2[k4], x3 = xr3[k4];
      a0 += x0.x*wv.x + x0.y*wv.y + x0.z*wv.z + x0.w*wv.w;
      a1 += x1.x*wv.x + x1.y*wv.y + x1.z*wv.z + x1.w*wv.w;
      a2 += x2.x*wv.x + x2.y*wv.y + x2.z*wv.z + x2.w*wv.w;
      a3 += x3.x*wv.x + x3.y*wv.y + x3.z*wv.z + x3.w*wv.w;
    }
    if (n0+0 < N) h[(size_t)(n0+0)*128 + ocg] = a0 + bb;
    if (n0+1 < N) h[(size_t)(n0+1)*128 + ocg] = a1 + bb;
    if (n0+2 < N) h[(size_t)(n0+2)*128 + ocg] = a2 + bb;
    if (n0+3 < N) h[(size_t)(n0+3)*128 + ocg] = a3 + bb;
  }
}

// ---------------- attention scalars layer 1: a1i/a1j [N,8] ----------------
__global__ void k_att1(const float* __restrict__ h, const float* __restrict__ att,
                       float* __restrict__ ai, float* __restrict__ aj, int N){
  int i = blockIdx.x*blockDim.x + threadIdx.x; // n*8 + head
  if (i >= N*8) return;
  int hd = i & 7;
  const float4* hp = (const float4*)(h + (size_t)(i>>3)*128 + hd*16);
  const float4* ap = (const float4*)(att + hd*32);
  float si = 0.f, sj = 0.f;
  #pragma unroll
  for (int c = 0; c < 4; ++c){
    float4 v = hp[c], A = ap[c], B = ap[4+c];
    si += v.x*A.x + v.y*A.y + v.z*A.z + v.w*A.w;
    sj += v.x*B.x + v.y*B.y + v.z*B.z + v.w*B.w;
  }
  ai[i] = si; aj[i] = sj;
}

// ---------------- layer-1 segment softmax + aggregate + bias + ELU ----------------
// one wave per node. Phase1: lane = (edge-slot = lane>>3, head = lane&7), online max/denom,
// butterfly-combine over xor {8,16,32}. Phase2: lane owns channels (2l,2l+1), head = l>>3.
__global__ __launch_bounds__(256) void k_agg1(const float* __restrict__ h1,
    const float* __restrict__ a1i, const float* __restrict__ a1j,
    const int* __restrict__ rowstart, const int* __restrict__ csr,
    const float* __restrict__ bias, float* __restrict__ x2, int N){
  int lane = threadIdx.x & 63;
  int n = (blockIdx.x*blockDim.x + threadIdx.x) >> 6;
  if (n >= N) return;
  int rs = rowstart[n], re = rowstart[n+1];
  int hd = lane & 7, grp = lane >> 3;
  float aih = a1i[n*8 + hd];
  float es0 = lrelu02(aih + a1j[n*8 + hd]);   // self loop
  float m    = (grp==0)? es0 : -INFINITY;
  float dsum = (grp==0)? 1.f : 0.f;
  for (int ei = rs + grp; ei < re; ei += 8){
    int s = csr[ei];
    float e = lrelu02(aih + a1j[s*8 + hd]);
    if (e > m){ dsum = dsum*__expf(m - e) + 1.f; m = e; }
    else dsum += __expf(e - m);
  }
  #pragma unroll
  for (int off = 8; off < 64; off <<= 1){
    float mo  = __shfl_xor(m, off);
    float dso = __shfl_xor(dsum, off);
    float M = fmaxf(m, mo);
    float t1 = (dsum > 0.f)? dsum*__expf(m - M) : 0.f;
    float t2 = (dso  > 0.f)? dso *__expf(mo - M) : 0.f;
    m = M; dsum = t1 + t2;
  }
  // redistribute: lane l needs head l>>3; lane (l>>3) in 0..7 holds exactly that head
  int hd2 = lane >> 3;
  float mh = __shfl(m, hd2);
  float dh = __shfl(dsum, hd2);
  float invd = 1.f/(dh + 1e-16f);
  float ai2 = a1i[n*8 + hd2];
  const float2* hv2 = (const float2*)h1;
  float acc0, acc1;
  {
    float e = lrelu02(ai2 + a1j[n*8 + hd2]);
    float w = __expf(e - mh)*invd;
    float2 hv = hv2[(size_t)n*64 + lane];
    acc0 = w*hv.x; acc1 = w*hv.y;
  }
  for (int ei = rs; ei < re; ++ei){
    int s = csr[ei];
    float e = lrelu02(ai2 + a1j[s*8 + hd2]);
    float w = __expf(e - mh)*invd;
    float2 hv = hv2[(size_t)s*64 + lane];   // 512B coalesced gather
    acc0 += w*hv.x; acc1 += w*hv.y;
  }
  float o0 = acc0 + bias[2*lane];
  float o1 = acc1 + bias[2*lane+1];
  o0 = (o0 > 0.f)? o0 : (__expf(o0) - 1.f);  // ELU fused
  o1 = (o1 > 0.f)? o1 : (__expf(o1) - 1.f);
  ((float2*)x2)[(size_t)n*64 + lane] = make_float2(o0, o1);
}

// ---------------- GEMM2: h2[N,40] = x2 @ W2^T + b2 ----------------
// Same 4-chain structure: thread = (oc = t%40, group = t/40), 4 nodes/thread,
// 32 nodes per block-iter. W2 (20 KB) in LDS k4-major.
__global__ __launch_bounds__(320) void k_gemm2(const float* __restrict__ x,
    const float* __restrict__ W, const float* __restrict__ b,
    float* __restrict__ h, int N){
  __shared__ float Wl[5120]; // 20 KB, k4-major: (oc,k) -> (k>>2)*160 + oc*4 + (k&3)
  for (int i = threadIdx.x; i < 5120; i += 320){
    int oc = i >> 7, k = i & 127;
    Wl[(k>>2)*160 + (oc<<2) + (k&3)] = W[i];
  }
  __syncthreads();
  int oc = threadIdx.x % 40;
  int grp = threadIdx.x / 40;  // 0..7
  const float4* W4 = (const float4*)Wl;
  float bb = b[oc];
  for (int n0 = blockIdx.x*32 + grp*4; n0 < N; n0 += gridDim.x*32){
    int m0 = min(n0+0, N-1), m1 = min(n0+1, N-1), m2 = min(n0+2, N-1), m3 = min(n0+3, N-1);
    const float4* xr0 = (const float4*)(x + (size_t)m0*128);
    const float4* xr1 = (const float4*)(x + (size_t)m1*128);
    const float4* xr2 = (const float4*)(x + (size_t)m2*128);
    const float4* xr3 = (const float4*)(x + (size_t)m3*128);
    float a0 = 0.f, a1 = 0.f, a2 = 0.f, a3 = 0.f;
    #pragma unroll 8
    for (int k4 = 0; k4 < 32; ++k4){
      float4 wv = W4[k4*40 + oc];
      float4 x0 = xr0[k4], x1 = xr1[k4], x2 = xr2[k4], x3 = xr3[k4];
      a0 += x0.x*wv.x + x0.y*wv.y + x0.z*wv.z + x0.w*wv.w;
      a1 += x1.x*wv.x + x1.y*wv.y + x1.z*wv.z + x1.w*wv.w;
      a2 += x2.x*wv.x + x2.y*wv.y + x2.z*wv.z + x2.w*wv.w;
      a3 += x3.x*wv.x + x3.y*wv.y + x3.z*wv.z + x3.w*wv.w;
    }
    if (n0+0 < N) h[(size_t)(n0+0)*40 + oc] = a0 + bb;
    if (n0+1 < N) h[(size_t)(n0+1)*40 + oc] = a1 + bb;
    if (n0+2 < N) h[(size_t)(n0+2)*40 + oc] = a2 + bb;
    if (n0+3 < N) h[(size_t)(n0+3)*40 + oc] = a3 + bb;
  }
}

__global__ void k_att2(const float* __restrict__ h, const float* __restrict__ att,
                       float* __restrict__ ai, float* __restrict__ aj, int N){
  int n = blockIdx.x*blockDim.x + threadIdx.x;
  if (n >= N) return;
  const float* hp = h + (size_t)n*40;
  float si = 0.f, sj = 0.f;
  #pragma unroll
  for (int c = 0; c < 40; ++c){ float v = hp[c]; si += v*att[c]; sj += v*att[40+c]; }
  ai[n] = si; aj[n] = sj;
}

// ---------------- layer-2 aggregate (+bias) + log_softmax ----------------
__global__ __launch_bounds__(256) void k_agg2(const float* __restrict__ h2,
    const float* __restrict__ a2i, const float* __restrict__ a2j,
    const int* __restrict__ rowstart, const int* __restrict__ csr,
    const float* __restrict__ bias, float* __restrict__ out, int N){
  int lane = threadIdx.x & 63;
  int n = (blockIdx.x*blockDim.x + threadIdx.x) >> 6;
  if (n >= N) return;
  int rs = rowstart[n], re = rowstart[n+1];
  float ai = a2i[n];
  float es = lrelu02(ai + a2j[n]);            // self loop
  float m    = (lane==0)? es : -INFINITY;
  float dsum = (lane==0)? 1.f : 0.f;
  for (int ei = rs + lane; ei < re; ei += 64){
    int s = csr[ei];
    float e = lrelu02(ai + a2j[s]);
    if (e > m){ dsum = dsum*__expf(m - e) + 1.f; m = e; }
    else dsum += __expf(e - m);
  }
  #pragma unroll
  for (int off = 1; off < 64; off <<= 1){
    float mo  = __shfl_xor(m, off);
    float dso = __shfl_xor(dsum, off);
    float M = fmaxf(m, mo);
    float t1 = (dsum > 0.f)? dsum*__expf(m - M) : 0.f;
    float t2 = (dso  > 0.f)? dso *__expf(mo - M) : 0.f;
    m = M; dsum = t1 + t2;
  }
  float invd = 1.f/(dsum + 1e-16f);
  bool act = lane < 40;
  float acc = 0.f;
  {
    float w = __expf(es - m)*invd;
    if (act) acc = w*h2[(size_t)n*40 + lane];
  }
  for (int ei = rs; ei < re; ++ei){
    int s = csr[ei];
    float e = lrelu02(ai + a2j[s]);
    float w = __expf(e - m)*invd;
    if (act) acc += w*h2[(size_t)s*40 + lane];
  }
  float v = acc + (act? bias[lane] : 0.f);
  float mv = act? v : -INFINITY;
  #pragma unroll
  for (int off = 1; off < 64; off <<= 1) mv = fmaxf(mv, __shfl_xor(mv, off));
  float se = act? __expf(v - mv) : 0.f;
  #pragma unroll
  for (int off = 1; off < 64; off <<= 1) se += __shfl_xor(se, off);
  if (act) out[(size_t)n*40 + lane] = v - mv - __logf(se);
}

extern "C" void kernel_launch(void* const* d_in, const int* in_sizes, int n_in,
                              void* d_out, int out_size, void* d_ws, size_t ws_size,
                              hipStream_t stream){
  const float* x     = (const float*)d_in[0];
  const int*   ei    = (const int*)  d_in[1];
  const float* W1    = (const float*)d_in[2];
  const float* b1    = (const float*)d_in[3];
  const float* att1  = (const float*)d_in[4];
  const float* bias1 = (const float*)d_in[5];
  const float* W2    = (const float*)d_in[6];
  const float* b2    = (const float*)d_in[7];
  const float* att2  = (const float*)d_in[8];
  const float* bias2 = (const float*)d_in[9];
  int N = in_sizes[0] / 128;
  int E = in_sizes[1] / 2;
  const int* src = ei;
  const int* dst = ei + E;

  char* ws = (char*)d_ws;
  size_t off = 0;
  auto alloc = [&](size_t bytes)->char*{
    char* p = ws + off; off += (bytes + 255) & ~(size_t)255; return p;
  };
  float* h1   = (float*)alloc((size_t)N*128*4);
  float* x2   = (float*)alloc((size_t)N*128*4);
  float* h2   = (float*)alloc((size_t)N*40*4);
  float* a1i  = (float*)alloc((size_t)N*8*4);
  float* a1j  = (float*)alloc((size_t)N*8*4);
  float* a2i  = (float*)alloc((size_t)N*4);
  float* a2j  = (float*)alloc((size_t)N*4);
  int*   deg  = (int*)  alloc((size_t)N*4*2);  // deg + fill contiguous (one memset)
  int*   fillc= deg + N;
  int*   rowst= (int*)  alloc((size_t)(N+1)*4);
  int*   csr  = (int*)  alloc((size_t)E*4);
  int*   bsum = (int*)  alloc(4096);

  hipMemsetAsync(deg, 0, (size_t)N*8, stream);
  int nblk = (N + 1023)/1024;
  k_count<<<(E+255)/256, 256, 0, stream>>>(dst, deg, E);
  k_scanA<<<nblk, 256, 0, stream>>>(deg, rowst, bsum, N);
  k_scanB<<<1, 128, 0, stream>>>(bsum, nblk);
  k_scanC<<<(N+255)/256, 256, 0, stream>>>(rowst, bsum, N, E);
  k_fill<<<(E+255)/256, 256, 0, stream>>>(src, dst, rowst, fillc, csr, E);

  dim3 g1(512, 2);
  k_gemm1<<<g1, 256, 0, stream>>>(x, W1, b1, h1, N);
  k_att1<<<(N*8+255)/256, 256, 0, stream>>>(h1, att1, a1i, a1j, N);
  k_agg1<<<(N*64+255)/256, 256, 0, stream>>>(h1, a1i, a1j, rowst, csr, bias1, x2, N);

  k_gemm2<<<1024, 320, 0, stream>>>(x2, W2, b2, h2, N);
  k_att2<<<(N+255)/256, 256, 0, stream>>>(h2, att2, a2i, a2j, N);
  k_agg2<<<(N*64+255)/256, 256, 0, stream>>>(h2, a2i, a2j, rowst, csr, bias2, (float*)d_out, N);
}

// Round 3
// 747.672 us; speedup vs baseline: 1.2891x; 1.2887x over previous
//
#include <hip/hip_runtime.h>
#include <math.h>

// 2-layer GAT, bf16-MFMA GEMMs: N nodes, E edges (+self loops per layer).
// L1: 128 -> 8 heads x16 (concat=128), ELU. L2: 128 -> 40, log_softmax.

typedef short bfrag __attribute__((ext_vector_type(8)));   // 8 bf16 (4 VGPRs)
typedef float f32x4 __attribute__((ext_vector_type(4)));

__device__ __forceinline__ float lrelu02(float x){ return x > 0.f ? x : 0.2f*x; }
__device__ __forceinline__ unsigned short f2bf(float f){
  unsigned int b = __float_as_uint(f);
  return (unsigned short)((b + 0x7fffu + ((b>>16)&1u)) >> 16);   // RNE
}
__device__ __forceinline__ float bfl(unsigned int u){ return __uint_as_float(u<<16); }
__device__ __forceinline__ float bfh(unsigned int u){ return __uint_as_float(u & 0xffff0000u); }

// ---------------- graph build: CSR by destination ----------------
__global__ void k_count(const int* __restrict__ dst, int* __restrict__ deg, int E){
  int i = blockIdx.x*blockDim.x + threadIdx.x;
  if (i < E) atomicAdd(&deg[dst[i]], 1);
}

__global__ void k_scanA(const int* __restrict__ deg, int* __restrict__ rowstart,
                        int* __restrict__ bsum, int N){
  __shared__ int lds[256];
  int t = threadIdx.x;
  int base = blockIdx.x*1024 + t*4;
  int v0 = (base+0<N)?deg[base+0]:0;
  int v1 = (base+1<N)?deg[base+1]:0;
  int v2 = (base+2<N)?deg[base+2]:0;
  int v3 = (base+3<N)?deg[base+3]:0;
  lds[t] = v0+v1+v2+v3;
  __syncthreads();
  for (int off=1; off<256; off<<=1){
    int x = (t>=off)? lds[t-off] : 0;
    __syncthreads();
    lds[t] += x;
    __syncthreads();
  }
  int run = (t==0)? 0 : lds[t-1];
  if (base+0<N) rowstart[base+0]=run;
  run += v0;
  if (base+1<N) rowstart[base+1]=run;
  run += v1;
  if (base+2<N) rowstart[base+2]=run;
  run += v2;
  if (base+3<N) rowstart[base+3]=run;
  if (t==255) bsum[blockIdx.x] = lds[255];
}

__global__ void k_scanB(int* bsum, int nblk){
  __shared__ int lds[128];
  int t = threadIdx.x;
  lds[t] = (t<nblk)? bsum[t] : 0;
  __syncthreads();
  for (int off=1; off<128; off<<=1){
    int x = (t>=off)? lds[t-off] : 0;
    __syncthreads();
    lds[t] += x;
    __syncthreads();
  }
  if (t<nblk) bsum[t] = (t==0)? 0 : lds[t-1];
}

__global__ void k_scanC(int* rowstart, const int* __restrict__ bsum, int N, int E){
  int i = blockIdx.x*blockDim.x + threadIdx.x;
  if (i < N) rowstart[i] += bsum[i>>10];
  if (i == 0) rowstart[N] = E;
}

__global__ void k_fill(const int* __restrict__ src, const int* __restrict__ dst,
                       const int* __restrict__ rowstart, int* __restrict__ fillc,
                       int* __restrict__ csr, int E){
  int i = blockIdx.x*blockDim.x + threadIdx.x;
  if (i < E){
    int d = dst[i];
    int pos = rowstart[d] + atomicAdd(&fillc[d], 1);
    csr[pos] = src[i];
  }
}

// ---------------- conversions to bf16 ----------------
__global__ void k_cvt_x(const float* __restrict__ x, unsigned short* __restrict__ xb, int n4){
  int i = blockIdx.x*blockDim.x + threadIdx.x;
  if (i >= n4) return;
  float4 v = ((const float4*)x)[i];
  ushort4 o = make_ushort4(f2bf(v.x), f2bf(v.y), f2bf(v.z), f2bf(v.w));
  ((ushort4*)xb)[i] = o;
}

// W1 [128,128] -> W1b; W2 [40,128] -> W2b padded to [48,128] (zeros)
__global__ void k_cvt_w(const float* __restrict__ W1, const float* __restrict__ W2,
                        unsigned short* __restrict__ W1b, unsigned short* __restrict__ W2b){
  int i = blockIdx.x*blockDim.x + threadIdx.x;
  if (i < 16384) W1b[i] = f2bf(W1[i]);
  else {
    int j = i - 16384;
    if (j < 6144){ int r = j >> 7; W2b[j] = (r < 40) ? f2bf(W2[j]) : (unsigned short)0; }
  }
}

// ---------------- GEMM1 (MFMA): h1b[N,128](bf16) = x_bf @ W1b^T + b1 ----------------
// one wave per 16-node group; 8 oc-tiles of 16; K=128 in 4 chunks of 32.
// A frag: lane holds x[m0+(lane&15)][q*32 + (lane>>4)*8 + 0..7]
// B frag: lane holds W[t*16+(lane&15)][q*32 + (lane>>4)*8 + 0..7]
// C/D:    col=lane&15, row=(lane>>4)*4+reg   [verified mapping]
__global__ __launch_bounds__(256) void k_gemm1(const unsigned short* __restrict__ xb,
    const unsigned short* __restrict__ Wb, const float* __restrict__ b1,
    unsigned short* __restrict__ h1b, int N){
  int wid  = (blockIdx.x*256 + threadIdx.x) >> 6;
  int lane = threadIdx.x & 63;
  int m0 = wid*16;
  if (m0 >= N) return;
  int col = lane & 15, quad = lane >> 4;
  const bfrag* A8 = (const bfrag*)(xb + (size_t)(m0+col)*128 + quad*8);
  f32x4 acc[8];
  #pragma unroll
  for (int t=0;t<8;t++){ acc[t][0]=0.f; acc[t][1]=0.f; acc[t][2]=0.f; acc[t][3]=0.f; }
  #pragma unroll
  for (int q=0;q<4;q++){
    bfrag a = A8[q*4];                        // advance q*32 bf16
    #pragma unroll
    for (int t=0;t<8;t++){
      const bfrag* Bp = (const bfrag*)(Wb + (size_t)(t*16+col)*128 + q*32 + quad*8);
      acc[t] = __builtin_amdgcn_mfma_f32_16x16x32_bf16(a, *Bp, acc[t], 0,0,0);
    }
  }
  #pragma unroll
  for (int t=0;t<8;t++){
    int c = t*16 + col;
    float bb = b1[c];
    #pragma unroll
    for (int r=0;r<4;r++){
      h1b[(size_t)(m0 + quad*4 + r)*128 + c] = f2bf(acc[t][r] + bb);
    }
  }
}

// ---------------- attention scalars layer 1: a1i/a1j [N,8] ----------------
__global__ void k_att1(const unsigned short* __restrict__ h1b, const float* __restrict__ att,
                       float* __restrict__ ai, float* __restrict__ aj, int N){
  int i = blockIdx.x*blockDim.x + threadIdx.x; // n*8 + head
  if (i >= N*8) return;
  int hd = i & 7;
  const uint4* hp = (const uint4*)(h1b + (size_t)(i>>3)*128 + hd*16);
  uint4 u0 = hp[0], u1 = hp[1];
  float v[16] = { bfl(u0.x),bfh(u0.x),bfl(u0.y),bfh(u0.y),bfl(u0.z),bfh(u0.z),bfl(u0.w),bfh(u0.w),
                  bfl(u1.x),bfh(u1.x),bfl(u1.y),bfh(u1.y),bfl(u1.z),bfh(u1.z),bfl(u1.w),bfh(u1.w) };
  const float* ap = att + hd*32;
  float si = 0.f, sj = 0.f;
  #pragma unroll
  for (int c = 0; c < 16; ++c){ si += v[c]*ap[c]; sj += v[c]*ap[16+c]; }
  ai[i] = si; aj[i] = sj;
}

// ---------------- layer-1 segment softmax + aggregate + bias + ELU ----------------
// one wave per node; h1 gathered as bf16 (256B/row), x2 written bf16.
__global__ __launch_bounds__(256) void k_agg1(const unsigned int* __restrict__ h1u,
    const float* __restrict__ a1i, const float* __restrict__ a1j,
    const int* __restrict__ rowstart, const int* __restrict__ csr,
    const float* __restrict__ bias, unsigned int* __restrict__ x2u, int N){
  int lane = threadIdx.x & 63;
  int n = (blockIdx.x*blockDim.x + threadIdx.x) >> 6;
  if (n >= N) return;
  int rs = rowstart[n], re = rowstart[n+1];
  int hd = lane & 7, grp = lane >> 3;
  float aih = a1i[n*8 + hd];
  float es0 = lrelu02(aih + a1j[n*8 + hd]);   // self loop
  float m    = (grp==0)? es0 : -INFINITY;
  float dsum = (grp==0)? 1.f : 0.f;
  for (int ei = rs + grp; ei < re; ei += 8){
    int s = csr[ei];
    float e = lrelu02(aih + a1j[s*8 + hd]);
    if (e > m){ dsum = dsum*__expf(m - e) + 1.f; m = e; }
    else dsum += __expf(e - m);
  }
  #pragma unroll
  for (int off = 8; off < 64; off <<= 1){
    float mo  = __shfl_xor(m, off);
    float dso = __shfl_xor(dsum, off);
    float M = fmaxf(m, mo);
    float t1 = (dsum > 0.f)? dsum*__expf(m - M) : 0.f;
    float t2 = (dso  > 0.f)? dso *__expf(mo - M) : 0.f;
    m = M; dsum = t1 + t2;
  }
  int hd2 = lane >> 3;
  float mh = __shfl(m, hd2);
  float dh = __shfl(dsum, hd2);
  float invd = 1.f/(dh + 1e-16f);
  float ai2 = a1i[n*8 + hd2];
  float acc0, acc1;
  {
    float e = lrelu02(ai2 + a1j[n*8 + hd2]);
    float w = __expf(e - mh)*invd;
    unsigned int u = h1u[(size_t)n*64 + lane];
    acc0 = w*bfl(u); acc1 = w*bfh(u);
  }
  for (int ei = rs; ei < re; ++ei){
    int s = csr[ei];
    float e = lrelu02(ai2 + a1j[s*8 + hd2]);
    float w = __expf(e - mh)*invd;
    unsigned int u = h1u[(size_t)s*64 + lane];   // 256B coalesced bf16 gather
    acc0 += w*bfl(u); acc1 += w*bfh(u);
  }
  float o0 = acc0 + bias[2*lane];
  float o1 = acc1 + bias[2*lane+1];
  o0 = (o0 > 0.f)? o0 : (__expf(o0) - 1.f);  // ELU fused
  o1 = (o1 > 0.f)? o1 : (__expf(o1) - 1.f);
  x2u[(size_t)n*64 + lane] = ((unsigned int)f2bf(o1) << 16) | (unsigned int)f2bf(o0);
}

// ---------------- GEMM2 (MFMA): h2[N,40](fp32) = x2_bf @ W2b^T + b2 ----------------
__global__ __launch_bounds__(256) void k_gemm2(const unsigned short* __restrict__ xb,
    const unsigned short* __restrict__ Wb, const float* __restrict__ b2,
    float* __restrict__ h2, int N){
  int wid  = (blockIdx.x*256 + threadIdx.x) >> 6;
  int lane = threadIdx.x & 63;
  int m0 = wid*16;
  if (m0 >= N) return;
  int col = lane & 15, quad = lane >> 4;
  const bfrag* A8 = (const bfrag*)(xb + (size_t)(m0+col)*128 + quad*8);
  f32x4 acc[3];
  #pragma unroll
  for (int t=0;t<3;t++){ acc[t][0]=0.f; acc[t][1]=0.f; acc[t][2]=0.f; acc[t][3]=0.f; }
  #pragma unroll
  for (int q=0;q<4;q++){
    bfrag a = A8[q*4];
    #pragma unroll
    for (int t=0;t<3;t++){
      const bfrag* Bp = (const bfrag*)(Wb + (size_t)(t*16+col)*128 + q*32 + quad*8);
      acc[t] = __builtin_amdgcn_mfma_f32_16x16x32_bf16(a, *Bp, acc[t], 0,0,0);
    }
  }
  #pragma unroll
  for (int t=0;t<3;t++){
    int c = t*16 + col;
    if (c < 40){
      float bb = b2[c];
      #pragma unroll
      for (int r=0;r<4;r++){
        h2[(size_t)(m0 + quad*4 + r)*40 + c] = acc[t][r] + bb;
      }
    }
  }
}

__global__ void k_att2(const float* __restrict__ h, const float* __restrict__ att,
                       float* __restrict__ ai, float* __restrict__ aj, int N){
  int n = blockIdx.x*blockDim.x + threadIdx.x;
  if (n >= N) return;
  const float* hp = h + (size_t)n*40;
  float si = 0.f, sj = 0.f;
  #pragma unroll
  for (int c = 0; c < 40; ++c){ float v = hp[c]; si += v*att[c]; sj += v*att[40+c]; }
  ai[n] = si; aj[n] = sj;
}

// ---------------- layer-2 aggregate (+bias) + log_softmax ----------------
__global__ __launch_bounds__(256) void k_agg2(const float* __restrict__ h2,
    const float* __restrict__ a2i, const float* __restrict__ a2j,
    const int* __restrict__ rowstart, const int* __restrict__ csr,
    const float* __restrict__ bias, float* __restrict__ out, int N){
  int lane = threadIdx.x & 63;
  int n = (blockIdx.x*blockDim.x + threadIdx.x) >> 6;
  if (n >= N) return;
  int rs = rowstart[n], re = rowstart[n+1];
  float ai = a2i[n];
  float es = lrelu02(ai + a2j[n]);            // self loop
  float m    = (lane==0)? es : -INFINITY;
  float dsum = (lane==0)? 1.f : 0.f;
  for (int ei = rs + lane; ei < re; ei += 64){
    int s = csr[ei];
    float e = lrelu02(ai + a2j[s]);
    if (e > m){ dsum = dsum*__expf(m - e) + 1.f; m = e; }
    else dsum += __expf(e - m);
  }
  #pragma unroll
  for (int off = 1; off < 64; off <<= 1){
    float mo  = __shfl_xor(m, off);
    float dso = __shfl_xor(dsum, off);
    float M = fmaxf(m, mo);
    float t1 = (dsum > 0.f)? dsum*__expf(m - M) : 0.f;
    float t2 = (dso  > 0.f)? dso *__expf(mo - M) : 0.f;
    m = M; dsum = t1 + t2;
  }
  float invd = 1.f/(dsum + 1e-16f);
  bool act = lane < 40;
  float acc = 0.f;
  {
    float w = __expf(es - m)*invd;
    if (act) acc = w*h2[(size_t)n*40 + lane];
  }
  for (int ei = rs; ei < re; ++ei){
    int s = csr[ei];
    float e = lrelu02(ai + a2j[s]);
    float w = __expf(e - m)*invd;
    if (act) acc += w*h2[(size_t)s*40 + lane];
  }
  float v = acc + (act? bias[lane] : 0.f);
  float mv = act? v : -INFINITY;
  #pragma unroll
  for (int off = 1; off < 64; off <<= 1) mv = fmaxf(mv, __shfl_xor(mv, off));
  float se = act? __expf(v - mv) : 0.f;
  #pragma unroll
  for (int off = 1; off < 64; off <<= 1) se += __shfl_xor(se, off);
  if (act) out[(size_t)n*40 + lane] = v - mv - __logf(se);
}

extern "C" void kernel_launch(void* const* d_in, const int* in_sizes, int n_in,
                              void* d_out, int out_size, void* d_ws, size_t ws_size,
                              hipStream_t stream){
  const float* x     = (const float*)d_in[0];
  const int*   ei    = (const int*)  d_in[1];
  const float* W1    = (const float*)d_in[2];
  const float* b1    = (const float*)d_in[3];
  const float* att1  = (const float*)d_in[4];
  const float* bias1 = (const float*)d_in[5];
  const float* W2    = (const float*)d_in[6];
  const float* b2    = (const float*)d_in[7];
  const float* att2  = (const float*)d_in[8];
  const float* bias2 = (const float*)d_in[9];
  int N = in_sizes[0] / 128;
  int E = in_sizes[1] / 2;
  const int* src = ei;
  const int* dst = ei + E;

  char* ws = (char*)d_ws;
  size_t off = 0;
  auto alloc = [&](size_t bytes)->char*{
    char* p = ws + off; off += (bytes + 255) & ~(size_t)255; return p;
  };
  unsigned short* xb  = (unsigned short*)alloc((size_t)N*128*2);
  unsigned short* h1b = (unsigned short*)alloc((size_t)N*128*2);
  unsigned short* x2b = (unsigned short*)alloc((size_t)N*128*2);
  float* h2   = (float*)alloc((size_t)N*40*4);
  float* a1i  = (float*)alloc((size_t)N*8*4);
  float* a1j  = (float*)alloc((size_t)N*8*4);
  float* a2i  = (float*)alloc((size_t)N*4);
  float* a2j  = (float*)alloc((size_t)N*4);
  unsigned short* W1b = (unsigned short*)alloc(16384*2);
  unsigned short* W2b = (unsigned short*)alloc(6144*2);  // 48 rows, padded
  int*   deg  = (int*)  alloc((size_t)N*4*2);  // deg + fill contiguous (one memset)
  int*   fillc= deg + N;
  int*   rowst= (int*)  alloc((size_t)(N+1)*4);
  int*   csr  = (int*)  alloc((size_t)E*4);
  int*   bsum = (int*)  alloc(4096);

  hipMemsetAsync(deg, 0, (size_t)N*8, stream);
  int nblk = (N + 1023)/1024;
  k_count<<<(E+255)/256, 256, 0, stream>>>(dst, deg, E);
  k_scanA<<<nblk, 256, 0, stream>>>(deg, rowst, bsum, N);
  k_scanB<<<1, 128, 0, stream>>>(bsum, nblk);
  k_scanC<<<(N+255)/256, 256, 0, stream>>>(rowst, bsum, N, E);
  k_fill<<<(E+255)/256, 256, 0, stream>>>(src, dst, rowst, fillc, csr, E);

  k_cvt_x<<<(N*32+255)/256, 256, 0, stream>>>(x, xb, N*32);
  k_cvt_w<<<(16384+6144+255)/256, 256, 0, stream>>>(W1, W2, W1b, W2b);

  int gblk = ((N+15)/16 + 3)/4;  // 4 waves/block, 16 nodes/wave
  k_gemm1<<<gblk, 256, 0, stream>>>(xb, W1b, b1, h1b, N);
  k_att1<<<(N*8+255)/256, 256, 0, stream>>>(h1b, att1, a1i, a1j, N);
  k_agg1<<<(N*64+255)/256, 256, 0, stream>>>((const unsigned int*)h1b, a1i, a1j, rowst, csr, bias1, (unsigned int*)x2b, N);

  k_gemm2<<<gblk, 256, 0, stream>>>(x2b, W2b, b2, h2, N);
  k_att2<<<(N+255)/256, 256, 0, stream>>>(h2, att2, a2i, a2j, N);
  k_agg2<<<(N*64+255)/256, 256, 0, stream>>>(h2, a2i, a2j, rowst, csr, bias2, (float*)d_out, N);
}

// Round 4
// 502.641 us; speedup vs baseline: 1.9175x; 1.4875x over previous
//
#include <hip/hip_runtime.h>
#include <math.h>

// 2-layer GAT, bf16-MFMA GEMMs, single-pass segment softmax (no max-sub; logits
// are O(1) so exp cannot overflow; normalization makes it mathematically equal).

typedef short bfrag __attribute__((ext_vector_type(8)));   // 8 bf16 (4 VGPRs)
typedef float f32x4 __attribute__((ext_vector_type(4)));

__device__ __forceinline__ float lrelu02(float x){ return x > 0.f ? x : 0.2f*x; }
__device__ __forceinline__ unsigned short f2bf(float f){
  unsigned int b = __float_as_uint(f);
  return (unsigned short)((b + 0x7fffu + ((b>>16)&1u)) >> 16);   // RNE
}
__device__ __forceinline__ float bfl(unsigned int u){ return __uint_as_float(u<<16); }
__device__ __forceinline__ float bfh(unsigned int u){ return __uint_as_float(u & 0xffff0000u); }

// ---------------- graph build: CSR by destination ----------------
__global__ void k_count(const int* __restrict__ dst, int* __restrict__ deg, int E){
  int i = blockIdx.x*blockDim.x + threadIdx.x;
  if (i < E) atomicAdd(&deg[dst[i]], 1);
}

__global__ void k_scanA(const int* __restrict__ deg, int* __restrict__ rowstart,
                        int* __restrict__ bsum, int N){
  __shared__ int lds[256];
  int t = threadIdx.x;
  int base = blockIdx.x*1024 + t*4;
  int v0 = (base+0<N)?deg[base+0]:0;
  int v1 = (base+1<N)?deg[base+1]:0;
  int v2 = (base+2<N)?deg[base+2]:0;
  int v3 = (base+3<N)?deg[base+3]:0;
  lds[t] = v0+v1+v2+v3;
  __syncthreads();
  for (int off=1; off<256; off<<=1){
    int x = (t>=off)? lds[t-off] : 0;
    __syncthreads();
    lds[t] += x;
    __syncthreads();
  }
  int run = (t==0)? 0 : lds[t-1];
  if (base+0<N) rowstart[base+0]=run;
  run += v0;
  if (base+1<N) rowstart[base+1]=run;
  run += v1;
  if (base+2<N) rowstart[base+2]=run;
  run += v2;
  if (base+3<N) rowstart[base+3]=run;
  if (t==255) bsum[blockIdx.x] = lds[255];
}

__global__ void k_scanB(int* bsum, int nblk){
  __shared__ int lds[128];
  int t = threadIdx.x;
  lds[t] = (t<nblk)? bsum[t] : 0;
  __syncthreads();
  for (int off=1; off<128; off<<=1){
    int x = (t>=off)? lds[t-off] : 0;
    __syncthreads();
    lds[t] += x;
    __syncthreads();
  }
  if (t<nblk) bsum[t] = (t==0)? 0 : lds[t-1];
}

__global__ void k_scanC(int* rowstart, const int* __restrict__ bsum, int N, int E){
  int i = blockIdx.x*blockDim.x + threadIdx.x;
  if (i < N) rowstart[i] += bsum[i>>10];
  if (i == 0) rowstart[N] = E;
}

__global__ void k_fill(const int* __restrict__ src, const int* __restrict__ dst,
                       const int* __restrict__ rowstart, int* __restrict__ fillc,
                       int* __restrict__ csr, int E){
  int i = blockIdx.x*blockDim.x + threadIdx.x;
  if (i < E){
    int d = dst[i];
    int pos = rowstart[d] + atomicAdd(&fillc[d], 1);
    csr[pos] = src[i];
  }
}

// ---------------- conversions to bf16 ----------------
__global__ void k_cvt_x(const float* __restrict__ x, unsigned short* __restrict__ xb, int n4){
  int i = blockIdx.x*blockDim.x + threadIdx.x;
  if (i >= n4) return;
  float4 v = ((const float4*)x)[i];
  ushort4 o = make_ushort4(f2bf(v.x), f2bf(v.y), f2bf(v.z), f2bf(v.w));
  ((ushort4*)xb)[i] = o;
}

__global__ void k_cvt_w(const float* __restrict__ W1, const float* __restrict__ W2,
                        unsigned short* __restrict__ W1b, unsigned short* __restrict__ W2b){
  int i = blockIdx.x*blockDim.x + threadIdx.x;
  if (i < 16384) W1b[i] = f2bf(W1[i]);
  else {
    int j = i - 16384;
    if (j < 6144){ int r = j >> 7; W2b[j] = (r < 40) ? f2bf(W2[j]) : (unsigned short)0; }
  }
}

// ---------------- GEMM1 (MFMA): h1b[N,128](bf16) = x_bf @ W1b^T + b1 ----------------
__global__ __launch_bounds__(256) void k_gemm1(const unsigned short* __restrict__ xb,
    const unsigned short* __restrict__ Wb, const float* __restrict__ b1,
    unsigned short* __restrict__ h1b, int N){
  int wid  = (blockIdx.x*256 + threadIdx.x) >> 6;
  int lane = threadIdx.x & 63;
  int m0 = wid*16;
  if (m0 >= N) return;
  int col = lane & 15, quad = lane >> 4;
  const bfrag* A8 = (const bfrag*)(xb + (size_t)(m0+col)*128 + quad*8);
  f32x4 acc[8];
  #pragma unroll
  for (int t=0;t<8;t++){ acc[t][0]=0.f; acc[t][1]=0.f; acc[t][2]=0.f; acc[t][3]=0.f; }
  #pragma unroll
  for (int q=0;q<4;q++){
    bfrag a = A8[q*4];
    #pragma unroll
    for (int t=0;t<8;t++){
      const bfrag* Bp = (const bfrag*)(Wb + (size_t)(t*16+col)*128 + q*32 + quad*8);
      acc[t] = __builtin_amdgcn_mfma_f32_16x16x32_bf16(a, *Bp, acc[t], 0,0,0);
    }
  }
  #pragma unroll
  for (int t=0;t<8;t++){
    int c = t*16 + col;
    float bb = b1[c];
    #pragma unroll
    for (int r=0;r<4;r++){
      h1b[(size_t)(m0 + quad*4 + r)*128 + c] = f2bf(acc[t][r] + bb);
    }
  }
}

// ---------------- attention scalars layer 1: a1i/a1j [N,8] ----------------
__global__ void k_att1(const unsigned short* __restrict__ h1b, const float* __restrict__ att,
                       float* __restrict__ ai, float* __restrict__ aj, int N){
  int i = blockIdx.x*blockDim.x + threadIdx.x; // n*8 + head
  if (i >= N*8) return;
  int hd = i & 7;
  const uint4* hp = (const uint4*)(h1b + (size_t)(i>>3)*128 + hd*16);
  uint4 u0 = hp[0], u1 = hp[1];
  float v[16] = { bfl(u0.x),bfh(u0.x),bfl(u0.y),bfh(u0.y),bfl(u0.z),bfh(u0.z),bfl(u0.w),bfh(u0.w),
                  bfl(u1.x),bfh(u1.x),bfl(u1.y),bfh(u1.y),bfl(u1.z),bfh(u1.z),bfl(u1.w),bfh(u1.w) };
  const float* ap = att + hd*32;
  float si = 0.f, sj = 0.f;
  #pragma unroll
  for (int c = 0; c < 16; ++c){ si += v[c]*ap[c]; sj += v[c]*ap[16+c]; }
  ai[i] = si; aj[i] = sj;
}

// ---------------- layer-1 fused softmax+aggregate (single pass) ----------------
// one wave per node; lane owns channels (2l,2l+1), head = l>>3. Per edge:
// w = exp(lrelu(ai+aj)); num += w*h1[s]; den += w. 8-deep clamped unroll for MLP.
// 32-bit indices -> SADDR-form loads.
__global__ __launch_bounds__(256) void k_agg1(const unsigned int* __restrict__ h1u,
    const float* __restrict__ a1i, const float* __restrict__ a1j,
    const int* __restrict__ rowstart, const int* __restrict__ csr,
    const float* __restrict__ bias, unsigned int* __restrict__ x2u, int N){
  int lane = threadIdx.x & 63;
  int n = (blockIdx.x*blockDim.x + threadIdx.x) >> 6;
  if (n >= N) return;
  int rs = rowstart[n], re = rowstart[n+1];
  unsigned hd = (unsigned)lane >> 3;
  float aih = a1i[((unsigned)n<<3) | hd];
  float acc0, acc1, den;
  {
    float w = __expf(lrelu02(aih + a1j[((unsigned)n<<3) | hd]));
    unsigned int u = h1u[((unsigned)n<<6) | (unsigned)lane];
    acc0 = w*bfl(u); acc1 = w*bfh(u); den = w;
  }
  int last = re - 1;
  for (int e0 = rs; e0 < re; e0 += 8){
    unsigned s0 = (unsigned)csr[min(e0+0,last)];
    unsigned s1 = (unsigned)csr[min(e0+1,last)];
    unsigned s2 = (unsigned)csr[min(e0+2,last)];
    unsigned s3 = (unsigned)csr[min(e0+3,last)];
    unsigned s4 = (unsigned)csr[min(e0+4,last)];
    unsigned s5 = (unsigned)csr[min(e0+5,last)];
    unsigned s6 = (unsigned)csr[min(e0+6,last)];
    unsigned s7 = (unsigned)csr[min(e0+7,last)];
    float j0 = a1j[(s0<<3)|hd], j1 = a1j[(s1<<3)|hd], j2 = a1j[(s2<<3)|hd], j3 = a1j[(s3<<3)|hd];
    float j4 = a1j[(s4<<3)|hd], j5 = a1j[(s5<<3)|hd], j6 = a1j[(s6<<3)|hd], j7 = a1j[(s7<<3)|hd];
    unsigned u0 = h1u[(s0<<6)|(unsigned)lane], u1 = h1u[(s1<<6)|(unsigned)lane];
    unsigned u2 = h1u[(s2<<6)|(unsigned)lane], u3 = h1u[(s3<<6)|(unsigned)lane];
    unsigned u4 = h1u[(s4<<6)|(unsigned)lane], u5 = h1u[(s5<<6)|(unsigned)lane];
    unsigned u6 = h1u[(s6<<6)|(unsigned)lane], u7 = h1u[(s7<<6)|(unsigned)lane];
    float w0 = (e0+0<re)? __expf(lrelu02(aih+j0)) : 0.f;
    float w1 = (e0+1<re)? __expf(lrelu02(aih+j1)) : 0.f;
    float w2 = (e0+2<re)? __expf(lrelu02(aih+j2)) : 0.f;
    float w3 = (e0+3<re)? __expf(lrelu02(aih+j3)) : 0.f;
    float w4 = (e0+4<re)? __expf(lrelu02(aih+j4)) : 0.f;
    float w5 = (e0+5<re)? __expf(lrelu02(aih+j5)) : 0.f;
    float w6 = (e0+6<re)? __expf(lrelu02(aih+j6)) : 0.f;
    float w7 = (e0+7<re)? __expf(lrelu02(aih+j7)) : 0.f;
    den += ((w0+w1)+(w2+w3)) + ((w4+w5)+(w6+w7));
    acc0 += w0*bfl(u0); acc1 += w0*bfh(u0);
    acc0 += w1*bfl(u1); acc1 += w1*bfh(u1);
    acc0 += w2*bfl(u2); acc1 += w2*bfh(u2);
    acc0 += w3*bfl(u3); acc1 += w3*bfh(u3);
    acc0 += w4*bfl(u4); acc1 += w4*bfh(u4);
    acc0 += w5*bfl(u5); acc1 += w5*bfh(u5);
    acc0 += w6*bfl(u6); acc1 += w6*bfh(u6);
    acc0 += w7*bfl(u7); acc1 += w7*bfh(u7);
  }
  float invd = 1.f/(den + 1e-16f);
  float o0 = acc0*invd + bias[2*lane];
  float o1 = acc1*invd + bias[2*lane+1];
  o0 = (o0 > 0.f)? o0 : (__expf(o0) - 1.f);  // ELU fused
  o1 = (o1 > 0.f)? o1 : (__expf(o1) - 1.f);
  x2u[((unsigned)n<<6) | (unsigned)lane] = ((unsigned int)f2bf(o1) << 16) | (unsigned int)f2bf(o0);
}

// ---------------- GEMM2 (MFMA): h2b[N,40](bf16) = x2_bf @ W2b^T + b2 ----------------
__global__ __launch_bounds__(256) void k_gemm2(const unsigned short* __restrict__ xb,
    const unsigned short* __restrict__ Wb, const float* __restrict__ b2,
    unsigned short* __restrict__ h2b, int N){
  int wid  = (blockIdx.x*256 + threadIdx.x) >> 6;
  int lane = threadIdx.x & 63;
  int m0 = wid*16;
  if (m0 >= N) return;
  int col = lane & 15, quad = lane >> 4;
  const bfrag* A8 = (const bfrag*)(xb + (size_t)(m0+col)*128 + quad*8);
  f32x4 acc[3];
  #pragma unroll
  for (int t=0;t<3;t++){ acc[t][0]=0.f; acc[t][1]=0.f; acc[t][2]=0.f; acc[t][3]=0.f; }
  #pragma unroll
  for (int q=0;q<4;q++){
    bfrag a = A8[q*4];
    #pragma unroll
    for (int t=0;t<3;t++){
      const bfrag* Bp = (const bfrag*)(Wb + (size_t)(t*16+col)*128 + q*32 + quad*8);
      acc[t] = __builtin_amdgcn_mfma_f32_16x16x32_bf16(a, *Bp, acc[t], 0,0,0);
    }
  }
  #pragma unroll
  for (int t=0;t<3;t++){
    int c = t*16 + col;
    if (c < 40){
      float bb = b2[c];
      #pragma unroll
      for (int r=0;r<4;r++){
        h2b[(size_t)(m0 + quad*4 + r)*40 + c] = f2bf(acc[t][r] + bb);
      }
    }
  }
}

__global__ void k_att2(const unsigned int* __restrict__ h2u, const float* __restrict__ att,
                       float* __restrict__ ai, float* __restrict__ aj, int N){
  int n = blockIdx.x*blockDim.x + threadIdx.x;
  if (n >= N) return;
  const unsigned int* hp = h2u + (size_t)n*20;
  float si = 0.f, sj = 0.f;
  #pragma unroll
  for (int c2 = 0; c2 < 20; ++c2){
    unsigned int u = hp[c2];
    float v0 = bfl(u), v1 = bfh(u);
    si += v0*att[2*c2] + v1*att[2*c2+1];
    sj += v0*att[40+2*c2] + v1*att[40+2*c2+1];
  }
  ai[n] = si; aj[n] = sj;
}

// ---------------- layer-2 fused softmax+aggregate + log_softmax ----------------
// one wave per node; lanes 0..19 own channels (2l,2l+1) of the 40; all lanes
// compute the (scalar) edge weight; single pass, 8-deep clamped unroll.
__global__ __launch_bounds__(256) void k_agg2(const unsigned int* __restrict__ h2u,
    const float* __restrict__ a2i, const float* __restrict__ a2j,
    const int* __restrict__ rowstart, const int* __restrict__ csr,
    const float* __restrict__ bias, float* __restrict__ out, int N){
  int lane = threadIdx.x & 63;
  int n = (blockIdx.x*blockDim.x + threadIdx.x) >> 6;
  if (n >= N) return;
  int rs = rowstart[n], re = rowstart[n+1];
  bool act = lane < 20;
  unsigned cl = act ? (unsigned)lane : 0u;
  float ai = a2i[n];
  float acc0, acc1, den;
  {
    float w = __expf(lrelu02(ai + a2j[n]));
    unsigned int u = h2u[(unsigned)n*20u + cl];
    acc0 = w*bfl(u); acc1 = w*bfh(u); den = w;
  }
  int last = re - 1;
  for (int e0 = rs; e0 < re; e0 += 8){
    unsigned s0 = (unsigned)csr[min(e0+0,last)];
    unsigned s1 = (unsigned)csr[min(e0+1,last)];
    unsigned s2 = (unsigned)csr[min(e0+2,last)];
    unsigned s3 = (unsigned)csr[min(e0+3,last)];
    unsigned s4 = (unsigned)csr[min(e0+4,last)];
    unsigned s5 = (unsigned)csr[min(e0+5,last)];
    unsigned s6 = (unsigned)csr[min(e0+6,last)];
    unsigned s7 = (unsigned)csr[min(e0+7,last)];
    float j0 = a2j[s0], j1 = a2j[s1], j2 = a2j[s2], j3 = a2j[s3];
    float j4 = a2j[s4], j5 = a2j[s5], j6 = a2j[s6], j7 = a2j[s7];
    unsigned u0 = h2u[s0*20u + cl], u1 = h2u[s1*20u + cl];
    unsigned u2 = h2u[s2*20u + cl], u3 = h2u[s3*20u + cl];
    unsigned u4 = h2u[s4*20u + cl], u5 = h2u[s5*20u + cl];
    unsigned u6 = h2u[s6*20u + cl], u7 = h2u[s7*20u + cl];
    float w0 = (e0+0<re)? __expf(lrelu02(ai+j0)) : 0.f;
    float w1 = (e0+1<re)? __expf(lrelu02(ai+j1)) : 0.f;
    float w2 = (e0+2<re)? __expf(lrelu02(ai+j2)) : 0.f;
    float w3 = (e0+3<re)? __expf(lrelu02(ai+j3)) : 0.f;
    float w4 = (e0+4<re)? __expf(lrelu02(ai+j4)) : 0.f;
    float w5 = (e0+5<re)? __expf(lrelu02(ai+j5)) : 0.f;
    float w6 = (e0+6<re)? __expf(lrelu02(ai+j6)) : 0.f;
    float w7 = (e0+7<re)? __expf(lrelu02(ai+j7)) : 0.f;
    den += ((w0+w1)+(w2+w3)) + ((w4+w5)+(w6+w7));
    acc0 += w0*bfl(u0); acc1 += w0*bfh(u0);
    acc0 += w1*bfl(u1); acc1 += w1*bfh(u1);
    acc0 += w2*bfl(u2); acc1 += w2*bfh(u2);
    acc0 += w3*bfl(u3); acc1 += w3*bfh(u3);
    acc0 += w4*bfl(u4); acc1 += w4*bfh(u4);
    acc0 += w5*bfl(u5); acc1 += w5*bfh(u5);
    acc0 += w6*bfl(u6); acc1 += w6*bfh(u6);
    acc0 += w7*bfl(u7); acc1 += w7*bfh(u7);
  }
  float invd = 1.f/(den + 1e-16f);
  float v0 = acc0*invd + bias[2*cl];
  float v1 = acc1*invd + bias[2*cl+1];
  float mv = act ? fmaxf(v0, v1) : -INFINITY;
  #pragma unroll
  for (int off = 1; off < 64; off <<= 1) mv = fmaxf(mv, __shfl_xor(mv, off));
  float se = act ? (__expf(v0 - mv) + __expf(v1 - mv)) : 0.f;
  #pragma unroll
  for (int off = 1; off < 64; off <<= 1) se += __shfl_xor(se, off);
  float ls = __logf(se);
  if (act) ((float2*)out)[(unsigned)n*20u + cl] = make_float2(v0 - mv - ls, v1 - mv - ls);
}

extern "C" void kernel_launch(void* const* d_in, const int* in_sizes, int n_in,
                              void* d_out, int out_size, void* d_ws, size_t ws_size,
                              hipStream_t stream){
  const float* x     = (const float*)d_in[0];
  const int*   ei    = (const int*)  d_in[1];
  const float* W1    = (const float*)d_in[2];
  const float* b1    = (const float*)d_in[3];
  const float* att1  = (const float*)d_in[4];
  const float* bias1 = (const float*)d_in[5];
  const float* W2    = (const float*)d_in[6];
  const float* b2    = (const float*)d_in[7];
  const float* att2  = (const float*)d_in[8];
  const float* bias2 = (const float*)d_in[9];
  int N = in_sizes[0] / 128;
  int E = in_sizes[1] / 2;
  const int* src = ei;
  const int* dst = ei + E;

  char* ws = (char*)d_ws;
  size_t off = 0;
  auto alloc = [&](size_t bytes)->char*{
    char* p = ws + off; off += (bytes + 255) & ~(size_t)255; return p;
  };
  unsigned short* xb  = (unsigned short*)alloc((size_t)N*128*2);
  unsigned short* h1b = (unsigned short*)alloc((size_t)N*128*2);
  unsigned short* x2b = (unsigned short*)alloc((size_t)N*128*2);
  unsigned short* h2b = (unsigned short*)alloc((size_t)N*40*2);
  float* a1i  = (float*)alloc((size_t)N*8*4);
  float* a1j  = (float*)alloc((size_t)N*8*4);
  float* a2i  = (float*)alloc((size_t)N*4);
  float* a2j  = (float*)alloc((size_t)N*4);
  unsigned short* W1b = (unsigned short*)alloc(16384*2);
  unsigned short* W2b = (unsigned short*)alloc(6144*2);
  int*   deg  = (int*)  alloc((size_t)N*4*2);  // deg + fill contiguous (one memset)
  int*   fillc= deg + N;
  int*   rowst= (int*)  alloc((size_t)(N+1)*4);
  int*   csr  = (int*)  alloc((size_t)E*4);
  int*   bsum = (int*)  alloc(4096);

  hipMemsetAsync(deg, 0, (size_t)N*8, stream);
  int nblk = (N + 1023)/1024;
  k_count<<<(E+255)/256, 256, 0, stream>>>(dst, deg, E);
  k_scanA<<<nblk, 256, 0, stream>>>(deg, rowst, bsum, N);
  k_scanB<<<1, 128, 0, stream>>>(bsum, nblk);
  k_scanC<<<(N+255)/256, 256, 0, stream>>>(rowst, bsum, N, E);
  k_fill<<<(E+255)/256, 256, 0, stream>>>(src, dst, rowst, fillc, csr, E);

  k_cvt_x<<<(N*32+255)/256, 256, 0, stream>>>(x, xb, N*32);
  k_cvt_w<<<(16384+6144+255)/256, 256, 0, stream>>>(W1, W2, W1b, W2b);

  int gblk = ((N+15)/16 + 3)/4;  // 4 waves/block, 16 nodes/wave
  k_gemm1<<<gblk, 256, 0, stream>>>(xb, W1b, b1, h1b, N);
  k_att1<<<(N*8+255)/256, 256, 0, stream>>>(h1b, att1, a1i, a1j, N);
  k_agg1<<<(N*64+255)/256, 256, 0, stream>>>((const unsigned int*)h1b, a1i, a1j, rowst, csr, bias1, (unsigned int*)x2b, N);

  k_gemm2<<<gblk, 256, 0, stream>>>(x2b, W2b, b2, h2b, N);
  k_att2<<<(N+255)/256, 256, 0, stream>>>((const unsigned int*)h2b, att2, a2i, a2j, N);
  k_agg2<<<(N*64+255)/256, 256, 0, stream>>>((const unsigned int*)h2b, a2i, a2j, rowst, csr, bias2, (float*)d_out, N);
}

// Round 5
// 465.159 us; speedup vs baseline: 2.0720x; 1.0806x over previous
//
#include <hip/hip_runtime.h>
#include <math.h>

// 2-layer GAT, bf16-MFMA GEMMs, single-pass segment softmax, XCD-partitioned
// CSR build (per-XCD node ranges -> no cross-XCD partial-line write thrash).

typedef short bfrag __attribute__((ext_vector_type(8)));   // 8 bf16 (4 VGPRs)
typedef float f32x4 __attribute__((ext_vector_type(4)));

__device__ __forceinline__ float lrelu02(float x){ return x > 0.f ? x : 0.2f*x; }
__device__ __forceinline__ unsigned short f2bf(float f){
  unsigned int b = __float_as_uint(f);
  return (unsigned short)((b + 0x7fffu + ((b>>16)&1u)) >> 16);   // RNE
}
__device__ __forceinline__ float bfl(unsigned int u){ return __uint_as_float(u<<16); }
__device__ __forceinline__ float bfh(unsigned int u){ return __uint_as_float(u & 0xffff0000u); }

// ---------------- graph build: CSR by destination, XCD-partitioned ----------------
// block b: node range [(b&7)*N/8, ...), edge chunk b>>3. All csr/deg writes for a
// node range come from one XCD -> L2 lines fill before eviction.
__global__ void k_count(const int* __restrict__ dst, int* __restrict__ deg, int E, int N){
  int xcd = blockIdx.x & 7;
  int blk = blockIdx.x >> 3;
  int nchunk = gridDim.x >> 3;
  int r0 = xcd*(N/8), r1 = (xcd==7)? N : (xcd+1)*(N/8);
  int per = (E + nchunk - 1)/nchunk;
  int lo = blk*per, hi = min(lo+per, E);
  for (int i = lo + threadIdx.x; i < hi; i += blockDim.x){
    int d = dst[i];
    if (d >= r0 && d < r1) atomicAdd(&deg[d], 1);
  }
}

__global__ void k_scanA(const int* __restrict__ deg, int* __restrict__ rowstart,
                        int* __restrict__ bsum, int N){
  __shared__ int lds[256];
  int t = threadIdx.x;
  int base = blockIdx.x*1024 + t*4;
  int v0 = (base+0<N)?deg[base+0]:0;
  int v1 = (base+1<N)?deg[base+1]:0;
  int v2 = (base+2<N)?deg[base+2]:0;
  int v3 = (base+3<N)?deg[base+3]:0;
  lds[t] = v0+v1+v2+v3;
  __syncthreads();
  for (int off=1; off<256; off<<=1){
    int x = (t>=off)? lds[t-off] : 0;
    __syncthreads();
    lds[t] += x;
    __syncthreads();
  }
  int run = (t==0)? 0 : lds[t-1];
  if (base+0<N) rowstart[base+0]=run;
  run += v0;
  if (base+1<N) rowstart[base+1]=run;
  run += v1;
  if (base+2<N) rowstart[base+2]=run;
  run += v2;
  if (base+3<N) rowstart[base+3]=run;
  if (t==255) bsum[blockIdx.x] = lds[255];
}

__global__ void k_scanB(int* bsum, int nblk){
  __shared__ int lds[128];
  int t = threadIdx.x;
  lds[t] = (t<nblk)? bsum[t] : 0;
  __syncthreads();
  for (int off=1; off<128; off<<=1){
    int x = (t>=off)? lds[t-off] : 0;
    __syncthreads();
    lds[t] += x;
    __syncthreads();
  }
  if (t<nblk) bsum[t] = (t==0)? 0 : lds[t-1];
}

__global__ void k_scanC(int* rowstart, const int* __restrict__ bsum, int N, int E){
  int i = blockIdx.x*blockDim.x + threadIdx.x;
  if (i < N) rowstart[i] += bsum[i>>10];
  if (i == 0) rowstart[N] = E;
}

__global__ void k_fill(const int* __restrict__ src, const int* __restrict__ dst,
                       const int* __restrict__ rowstart, int* __restrict__ fillc,
                       int* __restrict__ csr, int E, int N){
  int xcd = blockIdx.x & 7;
  int blk = blockIdx.x >> 3;
  int nchunk = gridDim.x >> 3;
  int r0 = xcd*(N/8), r1 = (xcd==7)? N : (xcd+1)*(N/8);
  int per = (E + nchunk - 1)/nchunk;
  int lo = blk*per, hi = min(lo+per, E);
  for (int i = lo + threadIdx.x; i < hi; i += blockDim.x){
    int d = dst[i];
    if (d >= r0 && d < r1){
      int pos = rowstart[d] + atomicAdd(&fillc[d], 1);
      csr[pos] = src[i];
    }
  }
}

// ---------------- conversions to bf16 ----------------
__global__ void k_cvt_x(const float* __restrict__ x, unsigned short* __restrict__ xb, int n4){
  int i = blockIdx.x*blockDim.x + threadIdx.x;
  if (i >= n4) return;
  float4 v = ((const float4*)x)[i];
  ushort4 o = make_ushort4(f2bf(v.x), f2bf(v.y), f2bf(v.z), f2bf(v.w));
  ((ushort4*)xb)[i] = o;
}

__global__ void k_cvt_w(const float* __restrict__ W1, const float* __restrict__ W2,
                        unsigned short* __restrict__ W1b, unsigned short* __restrict__ W2b){
  int i = blockIdx.x*blockDim.x + threadIdx.x;
  if (i < 16384) W1b[i] = f2bf(W1[i]);
  else {
    int j = i - 16384;
    if (j < 6144){ int r = j >> 7; W2b[j] = (r < 40) ? f2bf(W2[j]) : (unsigned short)0; }
  }
}

// ---------------- GEMM1 (MFMA): h1b[N,128](bf16) = x_bf @ W1b^T + b1 ----------------
__global__ __launch_bounds__(256) void k_gemm1(const unsigned short* __restrict__ xb,
    const unsigned short* __restrict__ Wb, const float* __restrict__ b1,
    unsigned short* __restrict__ h1b, int N){
  int wid  = (blockIdx.x*256 + threadIdx.x) >> 6;
  int lane = threadIdx.x & 63;
  int m0 = wid*16;
  if (m0 >= N) return;
  int col = lane & 15, quad = lane >> 4;
  const bfrag* A8 = (const bfrag*)(xb + (size_t)(m0+col)*128 + quad*8);
  f32x4 acc[8];
  #pragma unroll
  for (int t=0;t<8;t++){ acc[t][0]=0.f; acc[t][1]=0.f; acc[t][2]=0.f; acc[t][3]=0.f; }
  #pragma unroll
  for (int q=0;q<4;q++){
    bfrag a = A8[q*4];
    #pragma unroll
    for (int t=0;t<8;t++){
      const bfrag* Bp = (const bfrag*)(Wb + (size_t)(t*16+col)*128 + q*32 + quad*8);
      acc[t] = __builtin_amdgcn_mfma_f32_16x16x32_bf16(a, *Bp, acc[t], 0,0,0);
    }
  }
  #pragma unroll
  for (int t=0;t<8;t++){
    int c = t*16 + col;
    float bb = b1[c];
    #pragma unroll
    for (int r=0;r<4;r++){
      h1b[(size_t)(m0 + quad*4 + r)*128 + c] = f2bf(acc[t][r] + bb);
    }
  }
}

// ---------------- attention scalars layer 1: a1i/a1j [N,8] ----------------
__global__ void k_att1(const unsigned short* __restrict__ h1b, const float* __restrict__ att,
                       float* __restrict__ ai, float* __restrict__ aj, int N){
  int i = blockIdx.x*blockDim.x + threadIdx.x; // n*8 + head
  if (i >= N*8) return;
  int hd = i & 7;
  const uint4* hp = (const uint4*)(h1b + (size_t)(i>>3)*128 + hd*16);
  uint4 u0 = hp[0], u1 = hp[1];
  float v[16] = { bfl(u0.x),bfh(u0.x),bfl(u0.y),bfh(u0.y),bfl(u0.z),bfh(u0.z),bfl(u0.w),bfh(u0.w),
                  bfl(u1.x),bfh(u1.x),bfl(u1.y),bfh(u1.y),bfl(u1.z),bfh(u1.z),bfl(u1.w),bfh(u1.w) };
  const float* ap = att + hd*32;
  float si = 0.f, sj = 0.f;
  #pragma unroll
  for (int c = 0; c < 16; ++c){ si += v[c]*ap[c]; sj += v[c]*ap[16+c]; }
  ai[i] = si; aj[i] = sj;
}

// ---------------- layer-1 fused softmax+aggregate ----------------
// one wave per node. Weight phase: lane=(edge-slot=lane>>3, head=lane&7) -> one
// exp per lane covers 8 edges. Channel phase: lane owns channels (2l,2l+1),
// head hd2=l>>3; w redistributed via shfl (readlane for cs, bpermute for w).
__global__ __launch_bounds__(256) void k_agg1(const unsigned int* __restrict__ h1u,
    const float* __restrict__ a1i, const float* __restrict__ a1j,
    const int* __restrict__ rowstart, const int* __restrict__ csr,
    const float* __restrict__ bias, unsigned int* __restrict__ x2u, int N){
  int lane = threadIdx.x & 63;
  int n = (blockIdx.x*blockDim.x + threadIdx.x) >> 6;
  if (n >= N) return;
  int rs = rowstart[n], re = rowstart[n+1];
  unsigned hdw = (unsigned)lane & 7u;     // weight-phase head
  int esl = lane >> 3;                    // weight-phase edge slot
  int hd2 = lane >> 3;                    // channel-phase head
  float aiw = a1i[(unsigned)n*8u + hdw];
  float ai2 = __shfl(aiw, hd2);           // a1i[n,hd2]
  float jself = a1j[(unsigned)n*8u + (unsigned)hd2];
  float wself = __expf(lrelu02(ai2 + jself));
  unsigned un = h1u[(unsigned)n*64u + (unsigned)lane];
  float acc0 = wself*bfl(un), acc1 = wself*bfh(un);
  float denw = 0.f;                       // edge-denominator, weight layout
  int last = re - 1;
  for (int e0 = rs; e0 < re; e0 += 8){
    int ei = e0 + esl;
    unsigned cs = (unsigned)csr[min(ei, last)];
    float j = a1j[cs*8u + hdw];
    float w = (ei < re)? __expf(lrelu02(aiw + j)) : 0.f;
    denw += w;
    #pragma unroll
    for (int e = 0; e < 8; ++e){
      unsigned se = (unsigned)__shfl((int)cs, e*8);        // broadcast edge e's src
      float we = __shfl(w, e*8 + hd2);                     // its weight for my head
      unsigned u = h1u[se*64u + (unsigned)lane];
      acc0 += we*bfl(u); acc1 += we*bfh(u);
    }
  }
  // reduce den across edge-slots (xor bits 3..5), then move to channel layout
  #pragma unroll
  for (int off = 8; off < 64; off <<= 1) denw += __shfl_xor(denw, off);
  float den = __shfl(denw, hd2) + wself;
  float invd = 1.f/(den + 1e-16f);
  float o0 = acc0*invd + bias[2*lane];
  float o1 = acc1*invd + bias[2*lane+1];
  o0 = (o0 > 0.f)? o0 : (__expf(o0) - 1.f);  // ELU fused
  o1 = (o1 > 0.f)? o1 : (__expf(o1) - 1.f);
  x2u[(unsigned)n*64u + (unsigned)lane] = ((unsigned int)f2bf(o1) << 16) | (unsigned int)f2bf(o0);
}

// ---------------- GEMM2 (MFMA): h2b[N,40](bf16) = x2_bf @ W2b^T + b2 ----------------
__global__ __launch_bounds__(256) void k_gemm2(const unsigned short* __restrict__ xb,
    const unsigned short* __restrict__ Wb, const float* __restrict__ b2,
    unsigned short* __restrict__ h2b, int N){
  int wid  = (blockIdx.x*256 + threadIdx.x) >> 6;
  int lane = threadIdx.x & 63;
  int m0 = wid*16;
  if (m0 >= N) return;
  int col = lane & 15, quad = lane >> 4;
  const bfrag* A8 = (const bfrag*)(xb + (size_t)(m0+col)*128 + quad*8);
  f32x4 acc[3];
  #pragma unroll
  for (int t=0;t<3;t++){ acc[t][0]=0.f; acc[t][1]=0.f; acc[t][2]=0.f; acc[t][3]=0.f; }
  #pragma unroll
  for (int q=0;q<4;q++){
    bfrag a = A8[q*4];
    #pragma unroll
    for (int t=0;t<3;t++){
      const bfrag* Bp = (const bfrag*)(Wb + (size_t)(t*16+col)*128 + q*32 + quad*8);
      acc[t] = __builtin_amdgcn_mfma_f32_16x16x32_bf16(a, *Bp, acc[t], 0,0,0);
    }
  }
  #pragma unroll
  for (int t=0;t<3;t++){
    int c = t*16 + col;
    if (c < 40){
      float bb = b2[c];
      #pragma unroll
      for (int r=0;r<4;r++){
        h2b[(size_t)(m0 + quad*4 + r)*40 + c] = f2bf(acc[t][r] + bb);
      }
    }
  }
}

__global__ void k_att2(const unsigned int* __restrict__ h2u, const float* __restrict__ att,
                       float* __restrict__ ai, float* __restrict__ aj, int N){
  int n = blockIdx.x*blockDim.x + threadIdx.x;
  if (n >= N) return;
  const unsigned int* hp = h2u + (size_t)n*20;
  float si = 0.f, sj = 0.f;
  #pragma unroll
  for (int c2 = 0; c2 < 20; ++c2){
    unsigned int u = hp[c2];
    float v0 = bfl(u), v1 = bfh(u);
    si += v0*att[2*c2] + v1*att[2*c2+1];
    sj += v0*att[40+2*c2] + v1*att[40+2*c2+1];
  }
  ai[n] = si; aj[n] = sj;
}

// ---------------- layer-2 fused softmax+aggregate + log_softmax ----------------
// TWO nodes per wave: half = lane>>5 picks the node; lanes 0..19 of each half own
// channel pairs. Per-half loops are exec-masked; final reductions use xor<32.
__global__ __launch_bounds__(256) void k_agg2(const unsigned int* __restrict__ h2u,
    const float* __restrict__ a2i, const float* __restrict__ a2j,
    const int* __restrict__ rowstart, const int* __restrict__ csr,
    const float* __restrict__ bias, float* __restrict__ out, int N){
  int lane = threadIdx.x & 63;
  int wid = (blockIdx.x*blockDim.x + threadIdx.x) >> 6;
  int half = lane >> 5, hl = lane & 31;
  int n = wid*2 + half;
  if (n >= N) return;
  int rs = rowstart[n], re = rowstart[n+1];
  bool act = hl < 20;
  unsigned cl = act ? (unsigned)hl : 0u;
  float ai = a2i[n];
  float wself = __expf(lrelu02(ai + a2j[n]));
  unsigned us = h2u[(unsigned)n*20u + cl];
  float acc0 = wself*bfl(us), acc1 = wself*bfh(us), den = wself;
  int last = re - 1;
  for (int e0 = rs; e0 < re; e0 += 4){
    unsigned s0 = (unsigned)csr[min(e0+0,last)];
    unsigned s1 = (unsigned)csr[min(e0+1,last)];
    unsigned s2 = (unsigned)csr[min(e0+2,last)];
    unsigned s3 = (unsigned)csr[min(e0+3,last)];
    float j0 = a2j[s0], j1 = a2j[s1], j2 = a2j[s2], j3 = a2j[s3];
    unsigned u0 = h2u[s0*20u + cl], u1 = h2u[s1*20u + cl];
    unsigned u2 = h2u[s2*20u + cl], u3 = h2u[s3*20u + cl];
    float w0 = (e0+0<re)? __expf(lrelu02(ai+j0)) : 0.f;
    float w1 = (e0+1<re)? __expf(lrelu02(ai+j1)) : 0.f;
    float w2 = (e0+2<re)? __expf(lrelu02(ai+j2)) : 0.f;
    float w3 = (e0+3<re)? __expf(lrelu02(ai+j3)) : 0.f;
    den += (w0+w1)+(w2+w3);
    acc0 += w0*bfl(u0); acc1 += w0*bfh(u0);
    acc0 += w1*bfl(u1); acc1 += w1*bfh(u1);
    acc0 += w2*bfl(u2); acc1 += w2*bfh(u2);
    acc0 += w3*bfl(u3); acc1 += w3*bfh(u3);
  }
  float invd = 1.f/(den + 1e-16f);
  float v0 = acc0*invd + bias[2*cl];
  float v1 = acc1*invd + bias[2*cl+1];
  float mv = act ? fmaxf(v0, v1) : -INFINITY;
  #pragma unroll
  for (int off = 1; off < 32; off <<= 1) mv = fmaxf(mv, __shfl_xor(mv, off));
  float se = act ? (__expf(v0 - mv) + __expf(v1 - mv)) : 0.f;
  #pragma unroll
  for (int off = 1; off < 32; off <<= 1) se += __shfl_xor(se, off);
  float ls = __logf(se);
  if (act) ((float2*)out)[(unsigned)n*20u + cl] = make_float2(v0 - mv - ls, v1 - mv - ls);
}

extern "C" void kernel_launch(void* const* d_in, const int* in_sizes, int n_in,
                              void* d_out, int out_size, void* d_ws, size_t ws_size,
                              hipStream_t stream){
  const float* x     = (const float*)d_in[0];
  const int*   ei    = (const int*)  d_in[1];
  const float* W1    = (const float*)d_in[2];
  const float* b1    = (const float*)d_in[3];
  const float* att1  = (const float*)d_in[4];
  const float* bias1 = (const float*)d_in[5];
  const float* W2    = (const float*)d_in[6];
  const float* b2    = (const float*)d_in[7];
  const float* att2  = (const float*)d_in[8];
  const float* bias2 = (const float*)d_in[9];
  int N = in_sizes[0] / 128;
  int E = in_sizes[1] / 2;
  const int* src = ei;
  const int* dst = ei + E;

  char* ws = (char*)d_ws;
  size_t off = 0;
  auto alloc = [&](size_t bytes)->char*{
    char* p = ws + off; off += (bytes + 255) & ~(size_t)255; return p;
  };
  unsigned short* xb  = (unsigned short*)alloc((size_t)N*128*2);
  unsigned short* h1b = (unsigned short*)alloc((size_t)N*128*2);
  unsigned short* x2b = (unsigned short*)alloc((size_t)N*128*2);
  unsigned short* h2b = (unsigned short*)alloc((size_t)N*40*2);
  float* a1i  = (float*)alloc((size_t)N*8*4);
  float* a1j  = (float*)alloc((size_t)N*8*4);
  float* a2i  = (float*)alloc((size_t)N*4);
  float* a2j  = (float*)alloc((size_t)N*4);
  unsigned short* W1b = (unsigned short*)alloc(16384*2);
  unsigned short* W2b = (unsigned short*)alloc(6144*2);
  int*   deg  = (int*)  alloc((size_t)N*4*2);  // deg + fill contiguous (one memset)
  int*   fillc= deg + N;
  int*   rowst= (int*)  alloc((size_t)(N+1)*4);
  int*   csr  = (int*)  alloc((size_t)E*4);
  int*   bsum = (int*)  alloc(4096);

  hipMemsetAsync(deg, 0, (size_t)N*8, stream);
  int nblk = (N + 1023)/1024;
  k_count<<<1024, 256, 0, stream>>>(dst, deg, E, N);
  k_scanA<<<nblk, 256, 0, stream>>>(deg, rowst, bsum, N);
  k_scanB<<<1, 128, 0, stream>>>(bsum, nblk);
  k_scanC<<<(N+255)/256, 256, 0, stream>>>(rowst, bsum, N, E);
  k_fill<<<1024, 256, 0, stream>>>(src, dst, rowst, fillc, csr, E, N);

  k_cvt_x<<<(N*32+255)/256, 256, 0, stream>>>(x, xb, N*32);
  k_cvt_w<<<(16384+6144+255)/256, 256, 0, stream>>>(W1, W2, W1b, W2b);

  int gblk = ((N+15)/16 + 3)/4;  // 4 waves/block, 16 nodes/wave
  k_gemm1<<<gblk, 256, 0, stream>>>(xb, W1b, b1, h1b, N);
  k_att1<<<(N*8+255)/256, 256, 0, stream>>>(h1b, att1, a1i, a1j, N);
  k_agg1<<<(N*64+255)/256, 256, 0, stream>>>((const unsigned int*)h1b, a1i, a1j, rowst, csr, bias1, (unsigned int*)x2b, N);

  k_gemm2<<<gblk, 256, 0, stream>>>(x2b, W2b, b2, h2b, N);
  k_att2<<<(N+255)/256, 256, 0, stream>>>((const unsigned int*)h2b, att2, a2i, a2j, N);
  int waves2 = (N+1)/2;
  k_agg2<<<(waves2+3)/4, 256, 0, stream>>>((const unsigned int*)h2b, a2i, a2j, rowst, csr, bias2, (float*)d_out, N);
}

// Round 6
// 434.019 us; speedup vs baseline: 2.2207x; 1.0717x over previous
//
#include <hip/hip_runtime.h>
#include <math.h>

// 2-layer GAT, bf16-MFMA GEMMs, single-pass segment softmax, XCD-partitioned
// CSR scatter, rank-based fill (no fill atomics), software-pipelined gathers.

typedef short bfrag __attribute__((ext_vector_type(8)));   // 8 bf16 (4 VGPRs)
typedef float f32x4 __attribute__((ext_vector_type(4)));

__device__ __forceinline__ float lrelu02(float x){ return x > 0.f ? x : 0.2f*x; }
__device__ __forceinline__ unsigned short f2bf(float f){
  unsigned int b = __float_as_uint(f);
  return (unsigned short)((b + 0x7fffu + ((b>>16)&1u)) >> 16);   // RNE
}
__device__ __forceinline__ float bfl(unsigned int u){ return __uint_as_float(u<<16); }
__device__ __forceinline__ float bfh(unsigned int u){ return __uint_as_float(u & 0xffff0000u); }

// ---------------- graph build ----------------
// pass 1: rank[i] = position of edge i within its dst bucket (atomic count).
__global__ void k_rank(const int* __restrict__ dst, int* __restrict__ deg,
                       int* __restrict__ rank, int E){
  int i = blockIdx.x*blockDim.x + threadIdx.x;
  if (i < E) rank[i] = atomicAdd(&deg[dst[i]], 1);
}

__global__ void k_scanA(const int* __restrict__ deg, int* __restrict__ rowstart,
                        int* __restrict__ bsum, int N){
  __shared__ int lds[256];
  int t = threadIdx.x;
  int base = blockIdx.x*1024 + t*4;
  int v0 = (base+0<N)?deg[base+0]:0;
  int v1 = (base+1<N)?deg[base+1]:0;
  int v2 = (base+2<N)?deg[base+2]:0;
  int v3 = (base+3<N)?deg[base+3]:0;
  lds[t] = v0+v1+v2+v3;
  __syncthreads();
  for (int off=1; off<256; off<<=1){
    int x = (t>=off)? lds[t-off] : 0;
    __syncthreads();
    lds[t] += x;
    __syncthreads();
  }
  int run = (t==0)? 0 : lds[t-1];
  if (base+0<N) rowstart[base+0]=run;
  run += v0;
  if (base+1<N) rowstart[base+1]=run;
  run += v1;
  if (base+2<N) rowstart[base+2]=run;
  run += v2;
  if (base+3<N) rowstart[base+3]=run;
  if (t==255) bsum[blockIdx.x] = lds[255];
}

__global__ void k_scanB(int* bsum, int nblk){
  __shared__ int lds[128];
  int t = threadIdx.x;
  lds[t] = (t<nblk)? bsum[t] : 0;
  __syncthreads();
  for (int off=1; off<128; off<<=1){
    int x = (t>=off)? lds[t-off] : 0;
    __syncthreads();
    lds[t] += x;
    __syncthreads();
  }
  if (t<nblk) bsum[t] = (t==0)? 0 : lds[t-1];
}

__global__ void k_scanC(int* rowstart, const int* __restrict__ bsum, int N, int E){
  int i = blockIdx.x*blockDim.x + threadIdx.x;
  if (i < N) rowstart[i] += bsum[i>>10];
  if (i == 0) rowstart[N] = E;
}

// pass 2: XCD-partitioned scatter (block b&7 owns node range -> csr lines are
// written by one XCD only; no cross-XCD partial-line write-allocate thrash).
__global__ void k_fillx(const int* __restrict__ src, const int* __restrict__ dst,
                        const int* __restrict__ rank, const int* __restrict__ rowstart,
                        int* __restrict__ csr, int E, int N){
  int xcd = blockIdx.x & 7;
  int blk = blockIdx.x >> 3;
  int nchunk = gridDim.x >> 3;
  int r0 = xcd*(N/8), r1 = (xcd==7)? N : (xcd+1)*(N/8);
  int per = (E + nchunk - 1)/nchunk;
  int lo = blk*per, hi = min(lo+per, E);
  for (int i = lo + threadIdx.x; i < hi; i += blockDim.x){
    int d = dst[i];
    if (d >= r0 && d < r1) csr[rowstart[d] + rank[i]] = src[i];
  }
}

// ---------------- conversions to bf16 ----------------
__global__ void k_cvt_x(const float* __restrict__ x, unsigned short* __restrict__ xb, int n4){
  int i = blockIdx.x*blockDim.x + threadIdx.x;
  if (i >= n4) return;
  float4 v = ((const float4*)x)[i];
  ushort4 o = make_ushort4(f2bf(v.x), f2bf(v.y), f2bf(v.z), f2bf(v.w));
  ((ushort4*)xb)[i] = o;
}

__global__ void k_cvt_w(const float* __restrict__ W1, const float* __restrict__ W2,
                        unsigned short* __restrict__ W1b, unsigned short* __restrict__ W2b){
  int i = blockIdx.x*blockDim.x + threadIdx.x;
  if (i < 16384) W1b[i] = f2bf(W1[i]);
  else {
    int j = i - 16384;
    if (j < 6144){ int r = j >> 7; W2b[j] = (r < 40) ? f2bf(W2[j]) : (unsigned short)0; }
  }
}

// ---------------- GEMM1 (MFMA): h1b[N,128](bf16) = x_bf @ W1b^T + b1 ----------------
__global__ __launch_bounds__(256) void k_gemm1(const unsigned short* __restrict__ xb,
    const unsigned short* __restrict__ Wb, const float* __restrict__ b1,
    unsigned short* __restrict__ h1b, int N){
  int wid  = (blockIdx.x*256 + threadIdx.x) >> 6;
  int lane = threadIdx.x & 63;
  int m0 = wid*16;
  if (m0 >= N) return;
  int col = lane & 15, quad = lane >> 4;
  const bfrag* A8 = (const bfrag*)(xb + (size_t)(m0+col)*128 + quad*8);
  f32x4 acc[8];
  #pragma unroll
  for (int t=0;t<8;t++){ acc[t][0]=0.f; acc[t][1]=0.f; acc[t][2]=0.f; acc[t][3]=0.f; }
  #pragma unroll
  for (int q=0;q<4;q++){
    bfrag a = A8[q*4];
    #pragma unroll
    for (int t=0;t<8;t++){
      const bfrag* Bp = (const bfrag*)(Wb + (size_t)(t*16+col)*128 + q*32 + quad*8);
      acc[t] = __builtin_amdgcn_mfma_f32_16x16x32_bf16(a, *Bp, acc[t], 0,0,0);
    }
  }
  #pragma unroll
  for (int t=0;t<8;t++){
    int c = t*16 + col;
    float bb = b1[c];
    #pragma unroll
    for (int r=0;r<4;r++){
      h1b[(size_t)(m0 + quad*4 + r)*128 + c] = f2bf(acc[t][r] + bb);
    }
  }
}

// ---------------- attention scalars layer 1: a1i/a1j [N,8] ----------------
__global__ void k_att1(const unsigned short* __restrict__ h1b, const float* __restrict__ att,
                       float* __restrict__ ai, float* __restrict__ aj, int N){
  int i = blockIdx.x*blockDim.x + threadIdx.x; // n*8 + head
  if (i >= N*8) return;
  int hd = i & 7;
  const uint4* hp = (const uint4*)(h1b + (size_t)(i>>3)*128 + hd*16);
  uint4 u0 = hp[0], u1 = hp[1];
  float v[16] = { bfl(u0.x),bfh(u0.x),bfl(u0.y),bfh(u0.y),bfl(u0.z),bfh(u0.z),bfl(u0.w),bfh(u0.w),
                  bfl(u1.x),bfh(u1.x),bfl(u1.y),bfh(u1.y),bfl(u1.z),bfh(u1.z),bfl(u1.w),bfh(u1.w) };
  const float* ap = att + hd*32;
  float si = 0.f, sj = 0.f;
  #pragma unroll
  for (int c = 0; c < 16; ++c){ si += v[c]*ap[c]; sj += v[c]*ap[16+c]; }
  ai[i] = si; aj[i] = sj;
}

// ---------------- layer-1 fused softmax+aggregate (software-pipelined) ----------------
// one wave per node. Weight phase: lane=(slot=lane>>3, head=lane&7) -> one exp per
// lane covers 8 edges. Channel phase: lane owns channels (2l,2l+1), head=l>>3.
// Next iteration's csr+a1j loads are issued before the current FMAs consume u[].
__global__ __launch_bounds__(256) void k_agg1(const unsigned int* __restrict__ h1u,
    const float* __restrict__ a1i, const float* __restrict__ a1j,
    const int* __restrict__ rowstart, const int* __restrict__ csr,
    const float* __restrict__ bias, unsigned int* __restrict__ x2u, int N){
  int lane = threadIdx.x & 63;
  int n = (blockIdx.x*blockDim.x + threadIdx.x) >> 6;
  if (n >= N) return;
  int rs = rowstart[n], re = rowstart[n+1];
  unsigned hdw = (unsigned)lane & 7u;     // weight-phase head
  int esl = lane >> 3;                    // weight-phase edge slot
  int hd2 = lane >> 3;                    // channel-phase head
  float aiw = a1i[(unsigned)n*8u + hdw];
  float ai2 = __shfl(aiw, hd2);           // a1i[n,hd2]
  float jself = a1j[(unsigned)n*8u + (unsigned)hd2];
  float wself = __expf(lrelu02(ai2 + jself));
  unsigned un = h1u[(unsigned)n*64u + (unsigned)lane];
  float acc0 = wself*bfl(un), acc1 = wself*bfh(un);
  float denw = 0.f;                       // edge-denominator, weight layout
  int last = re - 1;
  unsigned cs = 0; float j = 0.f;
  if (rs < re){ cs = (unsigned)csr[min(rs+esl, last)]; j = a1j[cs*8u + hdw]; }
  for (int e0 = rs; e0 < re; e0 += 8){
    float w = (e0+esl < re)? __expf(lrelu02(aiw + j)) : 0.f;
    denw += w;
    unsigned se[8]; float we[8];
    #pragma unroll
    for (int e = 0; e < 8; ++e){
      se[e] = (unsigned)__shfl((int)cs, e*8);
      we[e] = __shfl(w, e*8 + hd2);
    }
    if (e0 + 8 < re){                     // prefetch next iter (wave-uniform branch)
      cs = (unsigned)csr[min(e0+8+esl, last)];
      j = a1j[cs*8u + hdw];
    }
    unsigned u[8];
    #pragma unroll
    for (int e = 0; e < 8; ++e) u[e] = h1u[(size_t)se[e]*64u + (unsigned)lane];
    #pragma unroll
    for (int e = 0; e < 8; ++e){ acc0 += we[e]*bfl(u[e]); acc1 += we[e]*bfh(u[e]); }
  }
  #pragma unroll
  for (int off = 8; off < 64; off <<= 1) denw += __shfl_xor(denw, off);
  float den = __shfl(denw, hd2) + wself;
  float invd = 1.f/(den + 1e-16f);
  float o0 = acc0*invd + bias[2*lane];
  float o1 = acc1*invd + bias[2*lane+1];
  o0 = (o0 > 0.f)? o0 : (__expf(o0) - 1.f);  // ELU fused
  o1 = (o1 > 0.f)? o1 : (__expf(o1) - 1.f);
  x2u[(unsigned)n*64u + (unsigned)lane] = ((unsigned int)f2bf(o1) << 16) | (unsigned int)f2bf(o0);
}

// ---------------- GEMM2 (MFMA): h2b[N,40](bf16) = x2_bf @ W2b^T + b2 ----------------
__global__ __launch_bounds__(256) void k_gemm2(const unsigned short* __restrict__ xb,
    const unsigned short* __restrict__ Wb, const float* __restrict__ b2,
    unsigned short* __restrict__ h2b, int N){
  int wid  = (blockIdx.x*256 + threadIdx.x) >> 6;
  int lane = threadIdx.x & 63;
  int m0 = wid*16;
  if (m0 >= N) return;
  int col = lane & 15, quad = lane >> 4;
  const bfrag* A8 = (const bfrag*)(xb + (size_t)(m0+col)*128 + quad*8);
  f32x4 acc[3];
  #pragma unroll
  for (int t=0;t<3;t++){ acc[t][0]=0.f; acc[t][1]=0.f; acc[t][2]=0.f; acc[t][3]=0.f; }
  #pragma unroll
  for (int q=0;q<4;q++){
    bfrag a = A8[q*4];
    #pragma unroll
    for (int t=0;t<3;t++){
      const bfrag* Bp = (const bfrag*)(Wb + (size_t)(t*16+col)*128 + q*32 + quad*8);
      acc[t] = __builtin_amdgcn_mfma_f32_16x16x32_bf16(a, *Bp, acc[t], 0,0,0);
    }
  }
  #pragma unroll
  for (int t=0;t<3;t++){
    int c = t*16 + col;
    if (c < 40){
      float bb = b2[c];
      #pragma unroll
      for (int r=0;r<4;r++){
        h2b[(size_t)(m0 + quad*4 + r)*40 + c] = f2bf(acc[t][r] + bb);
      }
    }
  }
}

__global__ void k_att2(const unsigned int* __restrict__ h2u, const float* __restrict__ att,
                       float* __restrict__ ai, float* __restrict__ aj, int N){
  int n = blockIdx.x*blockDim.x + threadIdx.x;
  if (n >= N) return;
  const unsigned int* hp = h2u + (size_t)n*20;
  float si = 0.f, sj = 0.f;
  #pragma unroll
  for (int c2 = 0; c2 < 20; ++c2){
    unsigned int u = hp[c2];
    float v0 = bfl(u), v1 = bfh(u);
    si += v0*att[2*c2] + v1*att[2*c2+1];
    sj += v0*att[40+2*c2] + v1*att[40+2*c2+1];
  }
  ai[n] = si; aj[n] = sj;
}

// ---------------- layer-2 fused softmax+aggregate + log_softmax ----------------
// TWO nodes per wave (half = lane>>5); lanes 0..19 of each half own channel pairs.
// Software-pipelined: next 4 (csr, a2j) loads issued before current FMAs.
__global__ __launch_bounds__(256) void k_agg2(const unsigned int* __restrict__ h2u,
    const float* __restrict__ a2i, const float* __restrict__ a2j,
    const int* __restrict__ rowstart, const int* __restrict__ csr,
    const float* __restrict__ bias, float* __restrict__ out, int N){
  int lane = threadIdx.x & 63;
  int wid = (blockIdx.x*blockDim.x + threadIdx.x) >> 6;
  int half = lane >> 5, hl = lane & 31;
  int n = wid*2 + half;
  if (n >= N) return;
  int rs = rowstart[n], re = rowstart[n+1];
  bool act = hl < 20;
  unsigned cl = act ? (unsigned)hl : 0u;
  float ai = a2i[n];
  float wself = __expf(lrelu02(ai + a2j[n]));
  unsigned us = h2u[(unsigned)n*20u + cl];
  float acc0 = wself*bfl(us), acc1 = wself*bfh(us), den = wself;
  int last = re - 1;
  unsigned cs[4]; float cj[4];
  if (rs < re){
    #pragma unroll
    for (int k=0;k<4;k++){ cs[k] = (unsigned)csr[min(rs+k,last)]; cj[k] = a2j[cs[k]]; }
  }
  for (int e0 = rs; e0 < re; e0 += 4){
    unsigned u[4]; float w[4];
    #pragma unroll
    for (int k=0;k<4;k++) u[k] = h2u[cs[k]*20u + cl];
    #pragma unroll
    for (int k=0;k<4;k++) w[k] = (e0+k<re)? __expf(lrelu02(ai+cj[k])) : 0.f;
    if (e0 + 4 < re){                    // prefetch next iter
      #pragma unroll
      for (int k=0;k<4;k++){ unsigned t=(unsigned)csr[min(e0+4+k,last)]; cs[k]=t; cj[k]=a2j[t]; }
    }
    den += (w[0]+w[1])+(w[2]+w[3]);
    #pragma unroll
    for (int k=0;k<4;k++){ acc0 += w[k]*bfl(u[k]); acc1 += w[k]*bfh(u[k]); }
  }
  float invd = 1.f/(den + 1e-16f);
  float v0 = acc0*invd + bias[2*cl];
  float v1 = acc1*invd + bias[2*cl+1];
  float mv = act ? fmaxf(v0, v1) : -INFINITY;
  #pragma unroll
  for (int off = 1; off < 32; off <<= 1) mv = fmaxf(mv, __shfl_xor(mv, off));
  float se = act ? (__expf(v0 - mv) + __expf(v1 - mv)) : 0.f;
  #pragma unroll
  for (int off = 1; off < 32; off <<= 1) se += __shfl_xor(se, off);
  float ls = __logf(se);
  if (act) ((float2*)out)[(unsigned)n*20u + cl] = make_float2(v0 - mv - ls, v1 - mv - ls);
}

extern "C" void kernel_launch(void* const* d_in, const int* in_sizes, int n_in,
                              void* d_out, int out_size, void* d_ws, size_t ws_size,
                              hipStream_t stream){
  const float* x     = (const float*)d_in[0];
  const int*   ei    = (const int*)  d_in[1];
  const float* W1    = (const float*)d_in[2];
  const float* b1    = (const float*)d_in[3];
  const float* att1  = (const float*)d_in[4];
  const float* bias1 = (const float*)d_in[5];
  const float* W2    = (const float*)d_in[6];
  const float* b2    = (const float*)d_in[7];
  const float* att2  = (const float*)d_in[8];
  const float* bias2 = (const float*)d_in[9];
  int N = in_sizes[0] / 128;
  int E = in_sizes[1] / 2;
  const int* src = ei;
  const int* dst = ei + E;

  char* ws = (char*)d_ws;
  size_t off = 0;
  auto alloc = [&](size_t bytes)->char*{
    char* p = ws + off; off += (bytes + 255) & ~(size_t)255; return p;
  };
  unsigned short* xb  = (unsigned short*)alloc((size_t)N*128*2);
  unsigned short* h1b = (unsigned short*)alloc((size_t)N*128*2);
  unsigned short* x2b = (unsigned short*)alloc((size_t)N*128*2);
  unsigned short* h2b = (unsigned short*)alloc((size_t)N*40*2);
  float* a1i  = (float*)alloc((size_t)N*8*4);
  float* a1j  = (float*)alloc((size_t)N*8*4);
  float* a2i  = (float*)alloc((size_t)N*4);
  float* a2j  = (float*)alloc((size_t)N*4);
  unsigned short* W1b = (unsigned short*)alloc(16384*2);
  unsigned short* W2b = (unsigned short*)alloc(6144*2);
  int*   deg  = (int*)  alloc((size_t)N*4);
  int*   rank = (int*)  alloc((size_t)E*4);
  int*   rowst= (int*)  alloc((size_t)(N+1)*4);
  int*   csr  = (int*)  alloc((size_t)E*4);
  int*   bsum = (int*)  alloc(4096);

  hipMemsetAsync(deg, 0, (size_t)N*4, stream);
  int nblk = (N + 1023)/1024;
  k_rank<<<(E+255)/256, 256, 0, stream>>>(dst, deg, rank, E);
  k_scanA<<<nblk, 256, 0, stream>>>(deg, rowst, bsum, N);
  k_scanB<<<1, 128, 0, stream>>>(bsum, nblk);
  k_scanC<<<(N+255)/256, 256, 0, stream>>>(rowst, bsum, N, E);
  k_fillx<<<1024, 256, 0, stream>>>(src, dst, rank, rowst, csr, E, N);

  k_cvt_x<<<(N*32+255)/256, 256, 0, stream>>>(x, xb, N*32);
  k_cvt_w<<<(16384+6144+255)/256, 256, 0, stream>>>(W1, W2, W1b, W2b);

  int gblk = ((N+15)/16 + 3)/4;  // 4 waves/block, 16 nodes/wave
  k_gemm1<<<gblk, 256, 0, stream>>>(xb, W1b, b1, h1b, N);
  k_att1<<<(N*8+255)/256, 256, 0, stream>>>(h1b, att1, a1i, a1j, N);
  k_agg1<<<(N*64+255)/256, 256, 0, stream>>>((const unsigned int*)h1b, a1i, a1j, rowst, csr, bias1, (unsigned int*)x2b, N);

  k_gemm2<<<gblk, 256, 0, stream>>>(x2b, W2b, b2, h2b, N);
  k_att2<<<(N+255)/256, 256, 0, stream>>>((const unsigned int*)h2b, att2, a2i, a2j, N);
  int waves2 = (N+1)/2;
  k_agg2<<<(waves2+3)/4, 256, 0, stream>>>((const unsigned int*)h2b, a2i, a2j, rowst, csr, bias2, (float*)d_out, N);
}